// Round 1
// baseline (458.586 us; speedup 1.0000x reference)
//
#include <hip/hip_runtime.h>

namespace {

constexpr int B_ = 4, C_ = 32, H_ = 128, W_ = 128;
constexpr int HW_ = H_ * W_;
constexpr int MH_ = 4, MS_ = 512, HD_ = 8;

// ---------------- 1. NCHW -> NHWC transpose of x ----------------
__global__ void k_transpose(const float* __restrict__ x, float* __restrict__ x_hwc) {
  __shared__ float tile[C_][65];  // +1 pad: conflict-free
  int blk = blockIdx.x;
  int b = blk >> 8;               // 256 tiles of 64 pixels per batch
  int n0 = (blk & 255) << 6;
  int t = threadIdx.x;
#pragma unroll
  for (int i = 0; i < 8; ++i) {
    int l = t + (i << 8);
    int c = l >> 6, p = l & 63;
    tile[c][p] = x[((size_t)(b * C_ + c)) * HW_ + n0 + p];
  }
  __syncthreads();
#pragma unroll
  for (int i = 0; i < 8; ++i) {
    int l = t + (i << 8);
    int p = l >> 5, c = l & 31;
    x_hwc[((size_t)b * HW_ + n0 + p) * C_ + c] = tile[c][p];
  }
}

// ---------------- 2. per-(b,c) spatial mean ----------------
__global__ void k_mean(const float* __restrict__ x, float* __restrict__ y_avg) {
  int bc = blockIdx.x;
  int t = threadIdx.x;
  const float* p = x + (size_t)bc * HW_;
  float s = 0.f;
  for (int i = t; i < HW_; i += 256) s += p[i];
  __shared__ float red[256];
  red[t] = s;
  __syncthreads();
  for (int off = 128; off > 0; off >>= 1) {
    if (t < off) red[t] += red[t + off];
    __syncthreads();
  }
  if (t == 0) y_avg[bc] = red[0] * (1.f / HW_);
}

// ---------------- 3. SE MLPs (tiny) ----------------
__global__ void k_se(const float* __restrict__ y_avg,
                     const float* __restrict__ fs_w1, const float* __restrict__ fs_w2,
                     const float* __restrict__ fc_w1, const float* __restrict__ fc_w2,
                     float* __restrict__ y_sp, float* __restrict__ y_ch) {
  int t = threadIdx.x;            // 128 = B*C
  int b = t >> 5, c = t & 31;
  const float* ya = y_avg + b * 32;
  {
    float h0 = 0.f, h1 = 0.f;
#pragma unroll
    for (int j = 0; j < 32; ++j) { h0 += ya[j] * fs_w1[j]; h1 += ya[j] * fs_w1[32 + j]; }
    h0 = fmaxf(h0, 0.f); h1 = fmaxf(h1, 0.f);
    float z = h0 * fs_w2[c * 2 + 0] + h1 * fs_w2[c * 2 + 1];
    y_sp[t] = 1.f / (1.f + __expf(-z));
  }
  {
    float hh[4];
#pragma unroll
    for (int jj = 0; jj < 4; ++jj) {
      float s = 0.f;
#pragma unroll
      for (int j = 0; j < 32; ++j) s += ya[j] * fc_w1[jj * 32 + j];
      hh[jj] = fmaxf(s, 0.f);
    }
    float z = 0.f;
#pragma unroll
    for (int jj = 0; jj < 4; ++jj) z += hh[jj] * fc_w2[c * 4 + jj];
    y_ch[t] = 1.f / (1.f + __expf(-z));
  }
}

// ---------------- 4. fused offset-conv + DCNv2 ----------------
// One block = one image row (128 threads = pixels). x rows y-1..y+1 staged in
// LDS with zero-pad columns. Output x3 stored NHWC.
__global__ __launch_bounds__(128) void k_dcn(
    const float* __restrict__ x,      // NCHW
    const float* __restrict__ x_hwc,  // (B,HW,C)
    const float* __restrict__ off_w, const float* __restrict__ off_b,
    const float* __restrict__ dcn_w, const float* __restrict__ dcn_b,
    float* __restrict__ x3_hwc) {
  __shared__ float tile[96][130];     // [c*3+dy][1+x]; cols 0,129 = zero pad
  int blk = blockIdx.x;
  int b = blk >> 7;
  int y = blk & 127;
  int t = threadIdx.x;                // x coordinate
  for (int r = 0; r < 96; ++r) {
    int c = r / 3, dy = r % 3;
    int yy = y + dy - 1;
    tile[r][1 + t] = (yy >= 0 && yy < H_) ? x[((size_t)(b * C_ + c)) * HW_ + yy * W_ + t] : 0.f;
  }
  if (t < 2) {
    int col = (t == 0) ? 0 : 129;
    for (int r = 0; r < 96; ++r) tile[r][col] = 0.f;
  }
  __syncthreads();

  // --- offset conv: om[27] = conv3x3(x)[.,y,t] + off_b ---
  float om[27];
#pragma unroll
  for (int o = 0; o < 27; ++o) om[o] = off_b[o];
  for (int c = 0; c < 32; ++c) {
    float v[9];
#pragma unroll
    for (int dy = 0; dy < 3; ++dy)
#pragma unroll
      for (int dx = 0; dx < 3; ++dx)
        v[dy * 3 + dx] = tile[c * 3 + dy][t + dx];
    const float* wp = off_w + c * 9;  // off_w[o*288 + c*9 + tap]
#pragma unroll
    for (int o = 0; o < 27; ++o) {
      const float* w = wp + o * 288;
      float s = om[o];
#pragma unroll
      for (int tap = 0; tap < 9; ++tap) s += v[tap] * w[tap];
      om[o] = s;
    }
  }

  // --- DCN sampling + 32x(32*9) matmul ---
  float out[32];
#pragma unroll
  for (int o = 0; o < 32; ++o) out[o] = dcn_b[o];
  const float* xb = x_hwc + (size_t)b * HW_ * C_;

  for (int k = 0; k < 9; ++k) {
    int ky = k / 3 - 1, kx = k % 3 - 1;
    float py = (float)(y + ky) + om[2 * k];
    float px = (float)(t + kx) + om[2 * k + 1];
    float y0f = floorf(py), x0f = floorf(px);
    float wy = py - y0f, wx = px - x0f;
    int y0 = (int)y0f, x0 = (int)x0f;
    float mask = 1.f / (1.f + __expf(-om[18 + k]));

    float samp[32];
#pragma unroll
    for (int cc = 0; cc < 32; ++cc) samp[cc] = 0.f;

#pragma unroll
    for (int cy = 0; cy < 2; ++cy) {
      int yi = y0 + cy;
      float wgy = cy ? wy : 1.f - wy;
      if (yi < 0 || yi >= H_) continue;
#pragma unroll
      for (int cx = 0; cx < 2; ++cx) {
        int xi = x0 + cx;
        if (xi < 0 || xi >= W_) continue;
        float wgt = wgy * (cx ? wx : 1.f - wx);
        const float4* s4 = (const float4*)(xb + ((size_t)yi * W_ + xi) * C_);
#pragma unroll
        for (int q = 0; q < 8; ++q) {
          float4 v4 = s4[q];
          samp[q * 4 + 0] += wgt * v4.x;
          samp[q * 4 + 1] += wgt * v4.y;
          samp[q * 4 + 2] += wgt * v4.z;
          samp[q * 4 + 3] += wgt * v4.w;
        }
      }
    }
    // out[o] += mask * sum_c samp[c] * dcn_w[o][c][k]
    const float* wk = dcn_w + k;      // dcn_w[(o*32+c)*9 + k]
#pragma unroll
    for (int o = 0; o < 32; ++o) {
      const float* w = wk + o * 288;
      float s = 0.f;
#pragma unroll
      for (int cc = 0; cc < 32; ++cc) s += samp[cc] * w[cc * 9];
      out[o] += s * mask;
    }
  }

  float* dst = x3_hwc + ((size_t)b * HW_ + y * W_ + t) * C_;
  float4* d4 = (float4*)dst;
#pragma unroll
  for (int q = 0; q < 8; ++q) {
    float4 v4;
    v4.x = out[q * 4 + 0]; v4.y = out[q * 4 + 1];
    v4.z = out[q * 4 + 2]; v4.w = out[q * 4 + 3];
    d4[q] = v4;
  }
}

// ---------------- 5. switch conv1x1s + gating -> xo ----------------
__global__ void k_switch(const float* __restrict__ x_hwc, const float* __restrict__ x3_hwc,
                         const float* __restrict__ sw_w1, const float* __restrict__ sw_b1,
                         const float* __restrict__ sw_w2, const float* __restrict__ sw_b2,
                         const float* __restrict__ y_sp, const float* __restrict__ y_ch,
                         float* __restrict__ xo_hwc) {
  int pix = blockIdx.x * 256 + threadIdx.x;   // 0..65535
  int b = pix >> 14;
  float cat[64];
  const float4* xa = (const float4*)(x_hwc + (size_t)pix * C_);
  const float4* xb = (const float4*)(x3_hwc + (size_t)pix * C_);
#pragma unroll
  for (int q = 0; q < 8; ++q) {
    float4 v = xa[q];
    cat[q * 4 + 0] = v.x; cat[q * 4 + 1] = v.y; cat[q * 4 + 2] = v.z; cat[q * 4 + 3] = v.w;
  }
#pragma unroll
  for (int q = 0; q < 8; ++q) {
    float4 v = xb[q];
    cat[32 + q * 4 + 0] = v.x; cat[32 + q * 4 + 1] = v.y; cat[32 + q * 4 + 2] = v.z; cat[32 + q * 4 + 3] = v.w;
  }
  float h1v[32];
#pragma unroll
  for (int o = 0; o < 32; ++o) {
    float s = sw_b1[o];
    const float* w = sw_w1 + o * 64;
#pragma unroll
    for (int c2 = 0; c2 < 64; ++c2) s += cat[c2] * w[c2];
    h1v[o] = fmaxf(s, 0.f);
  }
  float z0 = sw_b2[0], z1 = sw_b2[1];
#pragma unroll
  for (int c2 = 0; c2 < 32; ++c2) { z0 += h1v[c2] * sw_w2[c2]; z1 += h1v[c2] * sw_w2[32 + c2]; }
  float s0 = 1.f / (1.f + __expf(-z0));
  float s1 = 1.f / (1.f + __expf(-z1));
  const float* ysp = y_sp + b * 32;
  const float* ych = y_ch + b * 32;
  float* dst = xo_hwc + (size_t)pix * C_;
#pragma unroll
  for (int c2 = 0; c2 < 32; ++c2)
    dst[c2] = cat[c2] + ysp[c2] * s0 + ych[c2] * s1;
}

// ---------------- 6. memory attention + final add ----------------
__global__ __launch_bounds__(256) void k_attn(const float* __restrict__ xo_hwc,
                                              const float* __restrict__ mem,
                                              float* __restrict__ out) {
  __shared__ float mlds[MH_ * MS_ * HD_];   // 16384 floats = 64 KB
  int t = threadIdx.x;
  for (int i = t; i < MH_ * MS_ * HD_; i += 256) mlds[i] = mem[i];
  __syncthreads();

  int pix = blockIdx.x * 256 + t;
  int b = pix >> 14;
  int n = pix & (HW_ - 1);

  float q[32];
  const float4* xa = (const float4*)(xo_hwc + (size_t)pix * C_);
#pragma unroll
  for (int i = 0; i < 8; ++i) {
    float4 v = xa[i];
    q[4 * i] = v.x; q[4 * i + 1] = v.y; q[4 * i + 2] = v.z; q[4 * i + 3] = v.w;
  }
  const float scale = 0.35355339059327373f;  // 1/sqrt(8)
  float rec[32];
#pragma unroll
  for (int h = 0; h < 4; ++h) {
    const float* mh = mlds + h * MS_ * HD_;
    float acc[8] = {0, 0, 0, 0, 0, 0, 0, 0};
    float l = 0.f;
    for (int m = 0; m < MS_; ++m) {
      const float4* mv = (const float4*)(mh + m * 8);
      float4 a = mv[0], bb = mv[1];
      float s = q[h * 8 + 0] * a.x + q[h * 8 + 1] * a.y + q[h * 8 + 2] * a.z + q[h * 8 + 3] * a.w +
                q[h * 8 + 4] * bb.x + q[h * 8 + 5] * bb.y + q[h * 8 + 6] * bb.z + q[h * 8 + 7] * bb.w;
      float p = __expf(s * scale);   // scores are small; no max-subtraction needed
      l += p;
      acc[0] += p * a.x; acc[1] += p * a.y; acc[2] += p * a.z; acc[3] += p * a.w;
      acc[4] += p * bb.x; acc[5] += p * bb.y; acc[6] += p * bb.z; acc[7] += p * bb.w;
    }
    float inv = 1.f / l;
#pragma unroll
    for (int d = 0; d < 8; ++d) rec[h * 8 + d] = acc[d] * inv;
  }
#pragma unroll
  for (int c2 = 0; c2 < 32; ++c2)
    out[((size_t)(b * C_ + c2)) * HW_ + n] = q[c2] + rec[c2];
}

}  // namespace

extern "C" void kernel_launch(void* const* d_in, const int* in_sizes, int n_in,
                              void* d_out, int out_size, void* d_ws, size_t ws_size,
                              hipStream_t stream) {
  const float* x     = (const float*)d_in[0];
  const float* fs_w1 = (const float*)d_in[1];
  const float* fs_w2 = (const float*)d_in[2];
  const float* fc_w1 = (const float*)d_in[3];
  const float* fc_w2 = (const float*)d_in[4];
  const float* sw_w1 = (const float*)d_in[5];
  const float* sw_b1 = (const float*)d_in[6];
  const float* sw_w2 = (const float*)d_in[7];
  const float* sw_b2 = (const float*)d_in[8];
  const float* off_w = (const float*)d_in[9];
  const float* off_b = (const float*)d_in[10];
  const float* dcn_w = (const float*)d_in[11];
  const float* dcn_b = (const float*)d_in[12];
  const float* memw  = (const float*)d_in[13];
  float* out = (float*)d_out;

  float* ws = (float*)d_ws;
  float* y_avg  = ws;                 // 128
  float* y_sp   = ws + 128;           // 128
  float* y_ch   = ws + 256;           // 128
  float* x_hwc  = ws + 512;           // 2M
  float* x3_hwc = x_hwc + (size_t)B_ * HW_ * C_;
  float* xo_hwc = x3_hwc + (size_t)B_ * HW_ * C_;

  hipLaunchKernelGGL(k_transpose, dim3(B_ * 256), dim3(256), 0, stream, x, x_hwc);
  hipLaunchKernelGGL(k_mean, dim3(B_ * C_), dim3(256), 0, stream, x, y_avg);
  hipLaunchKernelGGL(k_se, dim3(1), dim3(128), 0, stream,
                     y_avg, fs_w1, fs_w2, fc_w1, fc_w2, y_sp, y_ch);
  hipLaunchKernelGGL(k_dcn, dim3(B_ * H_), dim3(128), 0, stream,
                     x, x_hwc, off_w, off_b, dcn_w, dcn_b, x3_hwc);
  hipLaunchKernelGGL(k_switch, dim3(B_ * HW_ / 256), dim3(256), 0, stream,
                     x_hwc, x3_hwc, sw_w1, sw_b1, sw_w2, sw_b2, y_sp, y_ch, xo_hwc);
  hipLaunchKernelGGL(k_attn, dim3(B_ * HW_ / 256), dim3(256), 0, stream,
                     xo_hwc, memw, out);
}

// Round 2
// 396.379 us; speedup vs baseline: 1.1569x; 1.1569x over previous
//
#include <hip/hip_runtime.h>

namespace {

constexpr int B_ = 4, C_ = 32, H_ = 128, W_ = 128;
constexpr int HW_ = H_ * W_;
constexpr int MS_ = 512;

// ---------------- 1. NCHW -> NHWC transpose of x ----------------
__global__ void k_transpose(const float* __restrict__ x, float* __restrict__ x_hwc) {
  __shared__ float tile[C_][65];
  int blk = blockIdx.x;
  int b = blk >> 8;
  int n0 = (blk & 255) << 6;
  int t = threadIdx.x;
#pragma unroll
  for (int i = 0; i < 8; ++i) {
    int l = t + (i << 8);
    int c = l >> 6, p = l & 63;
    tile[c][p] = x[((size_t)(b * C_ + c)) * HW_ + n0 + p];
  }
  __syncthreads();
#pragma unroll
  for (int i = 0; i < 8; ++i) {
    int l = t + (i << 8);
    int p = l >> 5, c = l & 31;
    x_hwc[((size_t)b * HW_ + n0 + p) * C_ + c] = tile[c][p];
  }
}

// ---------------- 2. per-(b,c) spatial mean ----------------
__global__ void k_mean(const float* __restrict__ x, float* __restrict__ y_avg) {
  int bc = blockIdx.x;
  int t = threadIdx.x;
  const float* p = x + (size_t)bc * HW_;
  float s = 0.f;
  for (int i = t; i < HW_; i += 256) s += p[i];
  __shared__ float red[256];
  red[t] = s;
  __syncthreads();
  for (int off = 128; off > 0; off >>= 1) {
    if (t < off) red[t] += red[t + off];
    __syncthreads();
  }
  if (t == 0) y_avg[bc] = red[0] * (1.f / HW_);
}

// ---------------- 3. SE MLPs (tiny) ----------------
__global__ void k_se(const float* __restrict__ y_avg,
                     const float* __restrict__ fs_w1, const float* __restrict__ fs_w2,
                     const float* __restrict__ fc_w1, const float* __restrict__ fc_w2,
                     float* __restrict__ y_sp, float* __restrict__ y_ch) {
  int t = threadIdx.x;  // 128 = B*C
  int b = t >> 5, c = t & 31;
  const float* ya = y_avg + b * 32;
  {
    float h0 = 0.f, h1 = 0.f;
#pragma unroll
    for (int j = 0; j < 32; ++j) { h0 += ya[j] * fs_w1[j]; h1 += ya[j] * fs_w1[32 + j]; }
    h0 = fmaxf(h0, 0.f); h1 = fmaxf(h1, 0.f);
    float z = h0 * fs_w2[c * 2 + 0] + h1 * fs_w2[c * 2 + 1];
    y_sp[t] = 1.f / (1.f + __expf(-z));
  }
  {
    float hh[4];
#pragma unroll
    for (int jj = 0; jj < 4; ++jj) {
      float s = 0.f;
#pragma unroll
      for (int j = 0; j < 32; ++j) s += ya[j] * fc_w1[jj * 32 + j];
      hh[jj] = fmaxf(s, 0.f);
    }
    float z = 0.f;
#pragma unroll
    for (int jj = 0; jj < 4; ++jj) z += hh[jj] * fc_w2[c * 4 + jj];
    y_ch[t] = 1.f / (1.f + __expf(-z));
  }
}

// ---------------- 4. fused offset-conv + DCNv2, wave-split ----------------
// Block = 256 threads = 4 waves covering 64 pixels (half row).
// Phase 1: wave w computes om outputs [7w,7w+7) (6 for w=3) over all 32 ch
//          (weights wave-uniform -> s_load), writes to om_lds.
// Phase 2: wave w samples its 8-channel group, partial 32-out matmul,
//          partials reduced via LDS (aliases the dead x-tile), wave 0 writes.
constexpr int TILE_F = 32 * 3 * 67;   // 6432 floats (x tile, width 67 pad)
constexpr int OUTP_F = 3 * 64 * 36;   // 6912 floats (phase-2 partials)
constexpr int SHBUF_F = (TILE_F > OUTP_F ? TILE_F : OUTP_F);

__global__ __launch_bounds__(256, 4) void k_dcn(
    const float* __restrict__ x,      // NCHW
    const float* __restrict__ x_hwc,  // (B,HW,C)
    const float* __restrict__ off_w, const float* __restrict__ off_b,
    const float* __restrict__ dcn_w, const float* __restrict__ dcn_b,
    float* __restrict__ x3_hwc) {
  __shared__ float shbuf[SHBUF_F];
  __shared__ float om_lds[64][29];    // stride 29: conflict-free

  int blk = blockIdx.x;
  int b = blk >> 8;
  int rem = blk & 255;
  int y = rem >> 1;
  int x0 = (rem & 1) << 6;
  int t = threadIdx.x;
  int w = t >> 6;
  int pix = t & 63;

  // --- stage x tile: tile(c, r, j) = x[b, c, y+r-1, x0-1+j], j in [0,66) ---
  for (int i = t; i < 32 * 3 * 66; i += 256) {
    int c = i / 198;
    int r2 = i - c * 198;
    int r = r2 / 66;
    int j = r2 - r * 66;
    int yy = y + r - 1;
    int xx = x0 - 1 + j;
    float v = (yy >= 0 && yy < H_ && xx >= 0 && xx < W_)
                  ? x[((size_t)(b * C_ + c)) * HW_ + yy * W_ + xx] : 0.f;
    shbuf[c * 201 + r * 67 + j] = v;
  }
  __syncthreads();

  // --- phase 1: offset conv, o-split across waves ---
  int o0 = w * 7;
  int on = (w == 3) ? 6 : 7;
  {
    float om[7];
#pragma unroll
    for (int oi = 0; oi < 7; ++oi) om[oi] = (oi < on) ? off_b[o0 + oi] : 0.f;
    for (int c = 0; c < 32; ++c) {
      float v[9];
#pragma unroll
      for (int r = 0; r < 3; ++r)
#pragma unroll
        for (int dx = 0; dx < 3; ++dx)
          v[r * 3 + dx] = shbuf[c * 201 + r * 67 + pix + dx];
      const float* wp = off_w + c * 9;
#pragma unroll
      for (int oi = 0; oi < 7; ++oi) {
        if (oi >= on) break;
        const float* wo = wp + (o0 + oi) * 288;
        float s = om[oi];
#pragma unroll
        for (int tap = 0; tap < 9; ++tap) s += v[tap] * wo[tap];
        om[oi] = s;
      }
    }
    for (int oi = 0; oi < on; ++oi) om_lds[pix][o0 + oi] = om[oi];
  }
  __syncthreads();

  // --- phase 2: sampling + matmul, c-split across waves ---
  float omv[27];
#pragma unroll
  for (int o = 0; o < 27; ++o) omv[o] = om_lds[pix][o];

  float out[32];
#pragma unroll
  for (int o = 0; o < 32; ++o) out[o] = 0.f;

  const float* xb = x_hwc + (size_t)b * HW_ * C_;
  int c0 = w * 8;
  int px_i = x0 + pix;

  for (int k = 0; k < 9; ++k) {
    int ky = k / 3 - 1, kx = k % 3 - 1;
    float py = (float)(y + ky) + omv[2 * k];
    float px = (float)(px_i + kx) + omv[2 * k + 1];
    float y0f = floorf(py), x0f = floorf(px);
    float wy = py - y0f, wx = px - x0f;
    int yi0 = (int)y0f, xi0 = (int)x0f;
    float mask = 1.f / (1.f + __expf(-omv[18 + k]));

    float samp[8];
#pragma unroll
    for (int cc = 0; cc < 8; ++cc) samp[cc] = 0.f;

#pragma unroll
    for (int cy = 0; cy < 2; ++cy) {
      int yi = yi0 + cy;
      if (yi < 0 || yi >= H_) continue;
      float wgy = cy ? wy : 1.f - wy;
#pragma unroll
      for (int cx = 0; cx < 2; ++cx) {
        int xi = xi0 + cx;
        if (xi < 0 || xi >= W_) continue;
        float wgt = wgy * (cx ? wx : 1.f - wx);
        const float4* s4 = (const float4*)(xb + ((size_t)yi * W_ + xi) * C_ + c0);
        float4 a = s4[0], bb = s4[1];
        samp[0] += wgt * a.x;  samp[1] += wgt * a.y;
        samp[2] += wgt * a.z;  samp[3] += wgt * a.w;
        samp[4] += wgt * bb.x; samp[5] += wgt * bb.y;
        samp[6] += wgt * bb.z; samp[7] += wgt * bb.w;
      }
    }
    // out[o] += mask * sum_cc samp[cc] * dcn_w[o*288 + (c0+cc)*9 + k]
    const float* wk = dcn_w + (size_t)c0 * 9 + k;
#pragma unroll
    for (int o = 0; o < 32; ++o) {
      const float* wo = wk + o * 288;
      float s = 0.f;
#pragma unroll
      for (int cc = 0; cc < 8; ++cc) s += samp[cc] * wo[cc * 9];
      out[o] += s * mask;
    }
  }

  __syncthreads();  // x tile dead; shbuf reused for partials
  if (w > 0) {
    float* op = shbuf + (w - 1) * 2304 + pix * 36;
#pragma unroll
    for (int o = 0; o < 32; o += 4) {
      float4 v4; v4.x = out[o]; v4.y = out[o + 1]; v4.z = out[o + 2]; v4.w = out[o + 3];
      *(float4*)(op + o) = v4;
    }
  }
  __syncthreads();
  if (w == 0) {
    const float* p0 = shbuf + pix * 36;
    float* dst = x3_hwc + ((size_t)b * HW_ + y * W_ + px_i) * C_;
#pragma unroll
    for (int o = 0; o < 32; o += 4) {
      float4 a = *(const float4*)(p0 + o);
      float4 b4 = *(const float4*)(p0 + 2304 + o);
      float4 c4 = *(const float4*)(p0 + 4608 + o);
      float4 v4;
      v4.x = out[o]     + a.x + b4.x + c4.x + dcn_b[o];
      v4.y = out[o + 1] + a.y + b4.y + c4.y + dcn_b[o + 1];
      v4.z = out[o + 2] + a.z + b4.z + c4.z + dcn_b[o + 2];
      v4.w = out[o + 3] + a.w + b4.w + c4.w + dcn_b[o + 3];
      *(float4*)(dst + o) = v4;
    }
  }
}

// ---------------- 5. fused switch conv1x1s + gating + memory attention ----------------
// Block = 256 threads = 64 pixels x 4 groups (quad). Group g computes h1
// channels [8g,8g+8), z via quad shfl_xor, xo channels [8g,8g+8) == q of head g,
// then attention for head g. mem staged in LDS as [m][h][d] (64 KB exactly).
__global__ __launch_bounds__(256, 2) void k_swattn(
    const float* __restrict__ x_hwc, const float* __restrict__ x3_hwc,
    const float* __restrict__ sw_w1, const float* __restrict__ sw_b1,
    const float* __restrict__ sw_w2, const float* __restrict__ sw_b2,
    const float* __restrict__ y_sp, const float* __restrict__ y_ch,
    const float* __restrict__ mem, float* __restrict__ out) {
  __shared__ float mlds[MS_ * 32];  // [m][h*8+d], 64 KB
  int t = threadIdx.x;

  // stage mem[h][m][d] -> mlds[m*32 + h*8 + d], float4 granularity
  {
    const float4* m4 = (const float4*)mem;
    for (int i4 = t; i4 < 4096; i4 += 256) {
      int h = i4 >> 10;
      int r = i4 & 1023;
      int m = r >> 1;
      int dd = (r & 1) << 2;
      *(float4*)(mlds + m * 32 + h * 8 + dd) = m4[i4];
    }
  }
  __syncthreads();

  int pixl = t >> 2;
  int g = t & 3;
  int pix = blockIdx.x * 64 + pixl;
  int b = pix >> 14;
  int n = pix & (HW_ - 1);

  // load cat = [x ; x3] (64 floats)
  float cat[64];
  {
    const float4* xa = (const float4*)(x_hwc + (size_t)pix * C_);
    const float4* xb = (const float4*)(x3_hwc + (size_t)pix * C_);
#pragma unroll
    for (int q = 0; q < 8; ++q) {
      float4 v = xa[q];
      cat[q * 4 + 0] = v.x; cat[q * 4 + 1] = v.y; cat[q * 4 + 2] = v.z; cat[q * 4 + 3] = v.w;
    }
#pragma unroll
    for (int q = 0; q < 8; ++q) {
      float4 v = xb[q];
      cat[32 + q * 4 + 0] = v.x; cat[32 + q * 4 + 1] = v.y; cat[32 + q * 4 + 2] = v.z; cat[32 + q * 4 + 3] = v.w;
    }
  }

  // h1 channels [8g, 8g+8)
  float h1v[8];
#pragma unroll
  for (int oi = 0; oi < 8; ++oi) {
    int o = g * 8 + oi;
    float s = sw_b1[o];
    const float* wp = sw_w1 + o * 64;
#pragma unroll
    for (int c2 = 0; c2 < 64; ++c2) s += cat[c2] * wp[c2];
    h1v[oi] = fmaxf(s, 0.f);
  }
  float zp0 = 0.f, zp1 = 0.f;
#pragma unroll
  for (int oi = 0; oi < 8; ++oi) {
    zp0 += h1v[oi] * sw_w2[g * 8 + oi];
    zp1 += h1v[oi] * sw_w2[32 + g * 8 + oi];
  }
  zp0 += __shfl_xor(zp0, 1); zp0 += __shfl_xor(zp0, 2);
  zp1 += __shfl_xor(zp1, 1); zp1 += __shfl_xor(zp1, 2);
  float s0 = 1.f / (1.f + __expf(-(zp0 + sw_b2[0])));
  float s1 = 1.f / (1.f + __expf(-(zp1 + sw_b2[1])));

  // xo channels [8g,8g+8) == q of head g
  float qv[8];
#pragma unroll
  for (int d = 0; d < 8; ++d) {
    int c = g * 8 + d;
    qv[d] = cat[c] + y_sp[b * 32 + c] * s0 + y_ch[b * 32 + c] * s1;
  }

  // attention head g over 512 slots
  const float scale = 0.35355339059327373f;
  float qs[8];
#pragma unroll
  for (int d = 0; d < 8; ++d) qs[d] = qv[d] * scale;
  float acc[8];
#pragma unroll
  for (int d = 0; d < 8; ++d) acc[d] = 0.f;
  float l = 0.f;
  const float* mbase = mlds + g * 8;
#pragma unroll 4
  for (int m = 0; m < MS_; ++m) {
    const float* mp = mbase + m * 32;
    float4 a = *(const float4*)(mp);
    float4 bb = *(const float4*)(mp + 4);
    float s = qs[0] * a.x + qs[1] * a.y + qs[2] * a.z + qs[3] * a.w +
              qs[4] * bb.x + qs[5] * bb.y + qs[6] * bb.z + qs[7] * bb.w;
    float p = __expf(s);
    l += p;
    acc[0] += p * a.x;  acc[1] += p * a.y;  acc[2] += p * a.z;  acc[3] += p * a.w;
    acc[4] += p * bb.x; acc[5] += p * bb.y; acc[6] += p * bb.z; acc[7] += p * bb.w;
  }
  float inv = 1.f / l;
#pragma unroll
  for (int d = 0; d < 8; ++d) {
    int c = g * 8 + d;
    out[((size_t)(b * C_ + c)) * HW_ + n] = qv[d] + acc[d] * inv;
  }
}

}  // namespace

extern "C" void kernel_launch(void* const* d_in, const int* in_sizes, int n_in,
                              void* d_out, int out_size, void* d_ws, size_t ws_size,
                              hipStream_t stream) {
  const float* x     = (const float*)d_in[0];
  const float* fs_w1 = (const float*)d_in[1];
  const float* fs_w2 = (const float*)d_in[2];
  const float* fc_w1 = (const float*)d_in[3];
  const float* fc_w2 = (const float*)d_in[4];
  const float* sw_w1 = (const float*)d_in[5];
  const float* sw_b1 = (const float*)d_in[6];
  const float* sw_w2 = (const float*)d_in[7];
  const float* sw_b2 = (const float*)d_in[8];
  const float* off_w = (const float*)d_in[9];
  const float* off_b = (const float*)d_in[10];
  const float* dcn_w = (const float*)d_in[11];
  const float* dcn_b = (const float*)d_in[12];
  const float* memw  = (const float*)d_in[13];
  float* out = (float*)d_out;

  float* ws = (float*)d_ws;
  float* y_avg  = ws;                 // 128
  float* y_sp   = ws + 128;           // 128
  float* y_ch   = ws + 256;           // 128
  float* x_hwc  = ws + 512;
  float* x3_hwc = x_hwc + (size_t)B_ * HW_ * C_;

  hipLaunchKernelGGL(k_transpose, dim3(B_ * 256), dim3(256), 0, stream, x, x_hwc);
  hipLaunchKernelGGL(k_mean, dim3(B_ * C_), dim3(256), 0, stream, x, y_avg);
  hipLaunchKernelGGL(k_se, dim3(1), dim3(128), 0, stream,
                     y_avg, fs_w1, fs_w2, fc_w1, fc_w2, y_sp, y_ch);
  hipLaunchKernelGGL(k_dcn, dim3(B_ * H_ * 2), dim3(256), 0, stream,
                     x, x_hwc, off_w, off_b, dcn_w, dcn_b, x3_hwc);
  hipLaunchKernelGGL(k_swattn, dim3(B_ * HW_ / 64), dim3(256), 0, stream,
                     x_hwc, x3_hwc, sw_w1, sw_b1, sw_w2, sw_b2, y_sp, y_ch, memw, out);
}

// Round 3
// 273.006 us; speedup vs baseline: 1.6798x; 1.4519x over previous
//
#include <hip/hip_runtime.h>

namespace {

constexpr int B_ = 4, C_ = 32, H_ = 128, W_ = 128;
constexpr int HW_ = H_ * W_;
constexpr int MS_ = 512;

// ---------------- 0. weight pre-transpose for s_load-friendly layouts ----------
// off_wT[((c*9+tap)*4 + w)*8 + i] = off_w[((7w+i)*32 + c)*9 + tap]  (i<7|6, pad 0)
// dcn_wT[(c*9+k)*32 + o]          = dcn_w[((o)*32 + c)*9 + k]
__global__ void k_prep(const float* __restrict__ off_w, const float* __restrict__ dcn_w,
                       float* __restrict__ off_wT, float* __restrict__ dcn_wT) {
  int i = blockIdx.x * 256 + threadIdx.x;   // 0..9215
  if (i >= 9216) return;
  {
    int ii = i & 7;
    int w = (i >> 3) & 3;
    int ct = i >> 5;            // 0..287
    int c = ct / 9, tap = ct - c * 9;
    int o = 7 * w + ii;
    int on = (w == 3) ? 6 : 7;
    off_wT[i] = (ii < on) ? off_w[((size_t)o * 32 + c) * 9 + tap] : 0.f;
  }
  {
    int o = i & 31;
    int ck = i >> 5;            // c*9+k
    dcn_wT[i] = dcn_w[((size_t)o * 32 + (ck / 9)) * 9 + (ck % 9)];
  }
}

// ---------------- 1. NCHW -> NHWC transpose of x ----------------
__global__ void k_transpose(const float* __restrict__ x, float* __restrict__ x_hwc) {
  __shared__ float tile[C_][65];
  int blk = blockIdx.x;
  int b = blk >> 8;
  int n0 = (blk & 255) << 6;
  int t = threadIdx.x;
#pragma unroll
  for (int i = 0; i < 8; ++i) {
    int l = t + (i << 8);
    int c = l >> 6, p = l & 63;
    tile[c][p] = x[((size_t)(b * C_ + c)) * HW_ + n0 + p];
  }
  __syncthreads();
#pragma unroll
  for (int i = 0; i < 8; ++i) {
    int l = t + (i << 8);
    int p = l >> 5, c = l & 31;
    x_hwc[((size_t)b * HW_ + n0 + p) * C_ + c] = tile[c][p];
  }
}

// ---------------- 2. per-(b,c) spatial mean ----------------
__global__ void k_mean(const float* __restrict__ x, float* __restrict__ y_avg) {
  int bc = blockIdx.x;
  int t = threadIdx.x;
  const float* p = x + (size_t)bc * HW_;
  float s = 0.f;
  for (int i = t; i < HW_; i += 256) s += p[i];
  __shared__ float red[256];
  red[t] = s;
  __syncthreads();
  for (int off = 128; off > 0; off >>= 1) {
    if (t < off) red[t] += red[t + off];
    __syncthreads();
  }
  if (t == 0) y_avg[bc] = red[0] * (1.f / HW_);
}

// ---------------- 3. SE MLPs (tiny) ----------------
__global__ void k_se(const float* __restrict__ y_avg,
                     const float* __restrict__ fs_w1, const float* __restrict__ fs_w2,
                     const float* __restrict__ fc_w1, const float* __restrict__ fc_w2,
                     float* __restrict__ y_sp, float* __restrict__ y_ch) {
  int t = threadIdx.x;  // 128 = B*C
  int b = t >> 5, c = t & 31;
  const float* ya = y_avg + b * 32;
  {
    float h0 = 0.f, h1 = 0.f;
#pragma unroll
    for (int j = 0; j < 32; ++j) { h0 += ya[j] * fs_w1[j]; h1 += ya[j] * fs_w1[32 + j]; }
    h0 = fmaxf(h0, 0.f); h1 = fmaxf(h1, 0.f);
    float z = h0 * fs_w2[c * 2 + 0] + h1 * fs_w2[c * 2 + 1];
    y_sp[t] = 1.f / (1.f + __expf(-z));
  }
  {
    float hh[4];
#pragma unroll
    for (int jj = 0; jj < 4; ++jj) {
      float s = 0.f;
#pragma unroll
      for (int j = 0; j < 32; ++j) s += ya[j] * fc_w1[jj * 32 + j];
      hh[jj] = fmaxf(s, 0.f);
    }
    float z = 0.f;
#pragma unroll
    for (int jj = 0; jj < 4; ++jj) z += hh[jj] * fc_w2[c * 4 + jj];
    y_ch[t] = 1.f / (1.f + __expf(-z));
  }
}

// ---------------- 4. fused offset-conv + DCNv2, wave-split, scalar weights ----
constexpr int TILE_F = 32 * 3 * 67;   // 6432 floats (x tile, width 67 pad)
constexpr int OUTP_F = 3 * 64 * 36;   // 6912 floats (phase-2 partials)
constexpr int SHBUF_F = (TILE_F > OUTP_F ? TILE_F : OUTP_F);

__global__ __launch_bounds__(256, 4) void k_dcn(
    const float* __restrict__ x,      // NCHW
    const float* __restrict__ x_hwc,  // (B,HW,C)
    const float* __restrict__ off_wT, const float* __restrict__ off_b,
    const float* __restrict__ dcn_wT, const float* __restrict__ dcn_b,
    float* __restrict__ x3_hwc) {
  __shared__ float shbuf[SHBUF_F];
  __shared__ float om_lds[64][29];

  int blk = blockIdx.x;
  int b = blk >> 8;
  int rem = blk & 255;
  int y = rem >> 1;
  int x0 = (rem & 1) << 6;
  int t = threadIdx.x;
  int w = __builtin_amdgcn_readfirstlane(t >> 6);  // wave id -> SGPR
  int pix = t & 63;

  // --- stage x tile: tile(c, r, j) = x[b, c, y+r-1, x0-1+j], j in [0,66) ---
  for (int i = t; i < 32 * 3 * 66; i += 256) {
    int c = i / 198;
    int r2 = i - c * 198;
    int r = r2 / 66;
    int j = r2 - r * 66;
    int yy = y + r - 1;
    int xx = x0 - 1 + j;
    float v = (yy >= 0 && yy < H_ && xx >= 0 && xx < W_)
                  ? x[((size_t)(b * C_ + c)) * HW_ + yy * W_ + xx] : 0.f;
    shbuf[c * 201 + r * 67 + j] = v;
  }
  __syncthreads();

  // --- phase 1: offset conv, o-split across waves; weights via s_load ---
  int o0 = w * 7;
  int on = (w == 3) ? 6 : 7;
  {
    float om[7];
#pragma unroll
    for (int oi = 0; oi < 7; ++oi) om[oi] = (oi < on) ? off_b[o0 + oi] : 0.f;
    for (int c = 0; c < 32; ++c) {
      float v[9];
#pragma unroll
      for (int r = 0; r < 3; ++r)
#pragma unroll
        for (int dx = 0; dx < 3; ++dx)
          v[r * 3 + dx] = shbuf[c * 201 + r * 67 + pix + dx];
#pragma unroll
      for (int tap = 0; tap < 9; ++tap) {
        const float* wp = off_wT + (((size_t)(c * 9 + tap) * 4 + w) << 3);
        float4 w0 = *(const float4*)wp;
        float4 w1 = *(const float4*)(wp + 4);
        float vt = v[tap];
        om[0] += vt * w0.x; om[1] += vt * w0.y; om[2] += vt * w0.z; om[3] += vt * w0.w;
        om[4] += vt * w1.x; om[5] += vt * w1.y; om[6] += vt * w1.z;
      }
    }
    for (int oi = 0; oi < on; ++oi) om_lds[pix][o0 + oi] = om[oi];
  }
  __syncthreads();

  // --- phase 2: sampling + matmul, c-split across waves; weights via s_load ---
  float omv[27];
#pragma unroll
  for (int o = 0; o < 27; ++o) omv[o] = om_lds[pix][o];

  float out[32];
#pragma unroll
  for (int o = 0; o < 32; ++o) out[o] = 0.f;

  const float* xb = x_hwc + (size_t)b * HW_ * C_;
  int c0 = w * 8;   // scalar
  int px_i = x0 + pix;

  for (int k = 0; k < 9; ++k) {
    int ky = k / 3 - 1, kx = k % 3 - 1;
    float py = (float)(y + ky) + omv[2 * k];
    float px = (float)(px_i + kx) + omv[2 * k + 1];
    float y0f = floorf(py), x0f = floorf(px);
    float wy = py - y0f, wx = px - x0f;
    int yi0 = (int)y0f, xi0 = (int)x0f;
    float mask = 1.f / (1.f + __expf(-omv[18 + k]));

    float samp[8];
#pragma unroll
    for (int cc = 0; cc < 8; ++cc) samp[cc] = 0.f;

#pragma unroll
    for (int cy = 0; cy < 2; ++cy) {
      int yi = yi0 + cy;
      if (yi < 0 || yi >= H_) continue;
      float wgy = cy ? wy : 1.f - wy;
#pragma unroll
      for (int cx = 0; cx < 2; ++cx) {
        int xi = xi0 + cx;
        if (xi < 0 || xi >= W_) continue;
        float wgt = wgy * (cx ? wx : 1.f - wx);
        const float4* s4 = (const float4*)(xb + ((size_t)yi * W_ + xi) * C_ + c0);
        float4 a = s4[0], bb = s4[1];
        samp[0] += wgt * a.x;  samp[1] += wgt * a.y;
        samp[2] += wgt * a.z;  samp[3] += wgt * a.w;
        samp[4] += wgt * bb.x; samp[5] += wgt * bb.y;
        samp[6] += wgt * bb.z; samp[7] += wgt * bb.w;
      }
    }
#pragma unroll
    for (int cc = 0; cc < 8; ++cc) {
      float smc = samp[cc] * mask;
      const float4* wp4 = (const float4*)(dcn_wT + ((size_t)((c0 + cc) * 9 + k) << 5));
#pragma unroll
      for (int j = 0; j < 8; ++j) {
        float4 wv = wp4[j];
        out[4 * j + 0] += smc * wv.x;
        out[4 * j + 1] += smc * wv.y;
        out[4 * j + 2] += smc * wv.z;
        out[4 * j + 3] += smc * wv.w;
      }
    }
  }

  __syncthreads();  // x tile dead; shbuf reused for partials
  if (w > 0) {
    float* op = shbuf + (w - 1) * 2304 + pix * 36;
#pragma unroll
    for (int o = 0; o < 32; o += 4) {
      float4 v4; v4.x = out[o]; v4.y = out[o + 1]; v4.z = out[o + 2]; v4.w = out[o + 3];
      *(float4*)(op + o) = v4;
    }
  }
  __syncthreads();
  if (w == 0) {
    const float* p0 = shbuf + pix * 36;
    float* dst = x3_hwc + ((size_t)b * HW_ + y * W_ + px_i) * C_;
#pragma unroll
    for (int o = 0; o < 32; o += 4) {
      float4 a = *(const float4*)(p0 + o);
      float4 b4 = *(const float4*)(p0 + 2304 + o);
      float4 c4 = *(const float4*)(p0 + 4608 + o);
      float4 v4;
      v4.x = out[o]     + a.x + b4.x + c4.x + dcn_b[o];
      v4.y = out[o + 1] + a.y + b4.y + c4.y + dcn_b[o + 1];
      v4.z = out[o + 2] + a.z + b4.z + c4.z + dcn_b[o + 2];
      v4.w = out[o + 3] + a.w + b4.w + c4.w + dcn_b[o + 3];
      *(float4*)(dst + o) = v4;
    }
  }
}

// ---------------- 5. fused switch + gating + memory attention ----------------
// Block = 256 thr = 4 waves over the SAME 64 pixels; wave g = head g.
// h1 split: wave g computes h1[8g..8g+8) per pixel, z via 2KB LDS exchange.
// mem[g] addresses are wave-scalar -> s_load (no LDS tile, high occupancy).
__global__ __launch_bounds__(256, 4) void k_swattn(
    const float* __restrict__ x_hwc, const float* __restrict__ x3_hwc,
    const float* __restrict__ sw_w1, const float* __restrict__ sw_b1,
    const float* __restrict__ sw_w2, const float* __restrict__ sw_b2,
    const float* __restrict__ y_sp, const float* __restrict__ y_ch,
    const float* __restrict__ mem, float* __restrict__ out) {
  __shared__ float zbuf[2][4][64];
  int t = threadIdx.x;
  int g = __builtin_amdgcn_readfirstlane(t >> 6);  // head id -> SGPR
  int p = t & 63;
  int pix = blockIdx.x * 64 + p;
  int b = pix >> 14;
  int n = pix & (HW_ - 1);

  // load cat = [x ; x3] (64 floats)
  float cat[64];
  {
    const float4* xa = (const float4*)(x_hwc + (size_t)pix * C_);
    const float4* xb = (const float4*)(x3_hwc + (size_t)pix * C_);
#pragma unroll
    for (int q = 0; q < 8; ++q) {
      float4 v = xa[q];
      cat[q * 4 + 0] = v.x; cat[q * 4 + 1] = v.y; cat[q * 4 + 2] = v.z; cat[q * 4 + 3] = v.w;
    }
#pragma unroll
    for (int q = 0; q < 8; ++q) {
      float4 v = xb[q];
      cat[32 + q * 4 + 0] = v.x; cat[32 + q * 4 + 1] = v.y; cat[32 + q * 4 + 2] = v.z; cat[32 + q * 4 + 3] = v.w;
    }
  }

  // h1 channels [8g, 8g+8)  (weights scalar)
  float zp0 = 0.f, zp1 = 0.f;
#pragma unroll
  for (int oi = 0; oi < 8; ++oi) {
    int o = g * 8 + oi;
    float s = sw_b1[o];
    const float* wp = sw_w1 + o * 64;
#pragma unroll
    for (int c2 = 0; c2 < 64; ++c2) s += cat[c2] * wp[c2];
    s = fmaxf(s, 0.f);
    zp0 += s * sw_w2[o];
    zp1 += s * sw_w2[32 + o];
  }
  zbuf[0][g][p] = zp0;
  zbuf[1][g][p] = zp1;
  __syncthreads();
  float z0 = zbuf[0][0][p] + zbuf[0][1][p] + zbuf[0][2][p] + zbuf[0][3][p] + sw_b2[0];
  float z1 = zbuf[1][0][p] + zbuf[1][1][p] + zbuf[1][2][p] + zbuf[1][3][p] + sw_b2[1];
  float s0 = 1.f / (1.f + __expf(-z0));
  float s1 = 1.f / (1.f + __expf(-z1));

  // q = xo channels [8g, 8g+8)  (xo = x + gates; x3 only feeds the switch)
  float qv[8];
  {
    const float4* qa = (const float4*)(x_hwc + (size_t)pix * C_ + g * 8);
    const float4* ga = (const float4*)(y_sp + b * 32 + g * 8);
    const float4* gc = (const float4*)(y_ch + b * 32 + g * 8);
    float4 a0 = qa[0], a1 = qa[1];
    float4 p0 = ga[0], p1 = ga[1];
    float4 c0 = gc[0], c1 = gc[1];
    qv[0] = a0.x + p0.x * s0 + c0.x * s1;
    qv[1] = a0.y + p0.y * s0 + c0.y * s1;
    qv[2] = a0.z + p0.z * s0 + c0.z * s1;
    qv[3] = a0.w + p0.w * s0 + c0.w * s1;
    qv[4] = a1.x + p1.x * s0 + c1.x * s1;
    qv[5] = a1.y + p1.y * s0 + c1.y * s1;
    qv[6] = a1.z + p1.z * s0 + c1.z * s1;
    qv[7] = a1.w + p1.w * s0 + c1.w * s1;
  }

  // attention head g over 512 slots; mem via scalar loads
  const float scale = 0.35355339059327373f;
  float qs[8];
#pragma unroll
  for (int d = 0; d < 8; ++d) qs[d] = qv[d] * scale;
  float acc[8];
#pragma unroll
  for (int d = 0; d < 8; ++d) acc[d] = 0.f;
  float l = 0.f;
  const float4* m4 = (const float4*)(mem + (size_t)g * MS_ * 8);
#pragma unroll 4
  for (int m = 0; m < MS_; ++m) {
    float4 a = m4[m * 2], bb = m4[m * 2 + 1];
    float s = qs[0] * a.x + qs[1] * a.y + qs[2] * a.z + qs[3] * a.w +
              qs[4] * bb.x + qs[5] * bb.y + qs[6] * bb.z + qs[7] * bb.w;
    float pe = __expf(s);
    l += pe;
    acc[0] += pe * a.x;  acc[1] += pe * a.y;  acc[2] += pe * a.z;  acc[3] += pe * a.w;
    acc[4] += pe * bb.x; acc[5] += pe * bb.y; acc[6] += pe * bb.z; acc[7] += pe * bb.w;
  }
  float inv = 1.f / l;
#pragma unroll
  for (int d = 0; d < 8; ++d) {
    int c = g * 8 + d;
    out[((size_t)(b * C_ + c)) * HW_ + n] = qv[d] + acc[d] * inv;
  }
}

}  // namespace

extern "C" void kernel_launch(void* const* d_in, const int* in_sizes, int n_in,
                              void* d_out, int out_size, void* d_ws, size_t ws_size,
                              hipStream_t stream) {
  const float* x     = (const float*)d_in[0];
  const float* fs_w1 = (const float*)d_in[1];
  const float* fs_w2 = (const float*)d_in[2];
  const float* fc_w1 = (const float*)d_in[3];
  const float* fc_w2 = (const float*)d_in[4];
  const float* sw_w1 = (const float*)d_in[5];
  const float* sw_b1 = (const float*)d_in[6];
  const float* sw_w2 = (const float*)d_in[7];
  const float* sw_b2 = (const float*)d_in[8];
  const float* off_w = (const float*)d_in[9];
  const float* off_b = (const float*)d_in[10];
  const float* dcn_w = (const float*)d_in[11];
  const float* dcn_b = (const float*)d_in[12];
  const float* memw  = (const float*)d_in[13];
  float* out = (float*)d_out;

  float* ws = (float*)d_ws;
  float* y_avg  = ws;                 // 128
  float* y_sp   = ws + 128;           // 128
  float* y_ch   = ws + 256;           // 128
  float* x_hwc  = ws + 512;
  float* x3_hwc = x_hwc + (size_t)B_ * HW_ * C_;
  float* off_wT = x3_hwc + (size_t)B_ * HW_ * C_;  // 9216
  float* dcn_wT = off_wT + 9216;                   // 9216

  hipLaunchKernelGGL(k_prep, dim3(36), dim3(256), 0, stream, off_w, dcn_w, off_wT, dcn_wT);
  hipLaunchKernelGGL(k_transpose, dim3(B_ * 256), dim3(256), 0, stream, x, x_hwc);
  hipLaunchKernelGGL(k_mean, dim3(B_ * C_), dim3(256), 0, stream, x, y_avg);
  hipLaunchKernelGGL(k_se, dim3(1), dim3(128), 0, stream,
                     y_avg, fs_w1, fs_w2, fc_w1, fc_w2, y_sp, y_ch);
  hipLaunchKernelGGL(k_dcn, dim3(B_ * H_ * 2), dim3(256), 0, stream,
                     x, x_hwc, off_wT, off_b, dcn_wT, dcn_b, x3_hwc);
  hipLaunchKernelGGL(k_swattn, dim3(B_ * HW_ / 64), dim3(256), 0, stream,
                     x_hwc, x3_hwc, sw_w1, sw_b1, sw_w2, sw_b2, y_sp, y_ch, memw, out);
}

// Round 4
// 246.469 us; speedup vs baseline: 1.8606x; 1.1077x over previous
//
#include <hip/hip_runtime.h>
#include <hip/hip_bf16.h>

namespace {

constexpr int B_ = 4, C_ = 32, H_ = 128, W_ = 128;
constexpr int HW_ = H_ * W_;
constexpr int MS_ = 512;
// fold (1/sqrt(8)) * log2(e) into q so scores feed exp2 directly
#define QSCALE 0.5100975104f

typedef short bf16x8_t __attribute__((ext_vector_type(8)));
typedef float f32x4_t __attribute__((ext_vector_type(4)));

union U4S8 { uint4 u; bf16x8_t s; };
union BF2U { __hip_bfloat162 h; unsigned u; };

__device__ inline unsigned pk_bf16(float lo, float hi) {
  BF2U t; t.h = __float22bfloat162_rn(float2{lo, hi}); return t.u;
}

__device__ inline unsigned short f2bf(float f) {
  unsigned u = __float_as_uint(f);
  return (unsigned short)((u + 0x7FFF + ((u >> 16) & 1)) >> 16);
}

// ---------------- 0a. conv-weight pre-transpose (s_load layouts) ----------
__global__ void k_prep(const float* __restrict__ off_w, const float* __restrict__ dcn_w,
                       float* __restrict__ off_wT, float* __restrict__ dcn_wT) {
  int i = blockIdx.x * 256 + threadIdx.x;   // 0..9215
  if (i >= 9216) return;
  {
    int ii = i & 7;
    int w = (i >> 3) & 3;
    int ct = i >> 5;            // 0..287
    int c = ct / 9, tap = ct - c * 9;
    int o = 7 * w + ii;
    int on = (w == 3) ? 6 : 7;
    off_wT[i] = (ii < on) ? off_w[((size_t)o * 32 + c) * 9 + tap] : 0.f;
  }
  {
    int o = i & 31;
    int ck = i >> 5;            // c*9+k
    dcn_wT[i] = dcn_w[((size_t)o * 32 + (ck / 9)) * 9 + (ck % 9)];
  }
}

// ---------------- 0b. mem -> MFMA fragment buffers (bf16) ----------------
// aq[h][t16][lane][j]  (A of S^T = mem x q^T): lane<16: mem[h][t16*16+lane][j], else 0
// apv[h][t32][lane][j] (A of rec^T = memT x P): row d=lane&15, m=t32*32+(lane>>4)*8+j
//                      val = d<8 ? mem[h][m][d] : (d==8 ? 1 : 0)   (d==8 row => l-sum)
__global__ void k_prep_mem(const float* __restrict__ mem,
                           unsigned short* __restrict__ aq,
                           unsigned short* __restrict__ apv) {
  int i = blockIdx.x * 256 + threadIdx.x;
  if (i < 65536) {
    int j = i & 7;
    int l = (i >> 3) & 63;
    int t = (i >> 9) & 31;
    int h = i >> 14;
    float v = 0.f;
    if (l < 16) v = mem[((size_t)h * MS_ + t * 16 + l) * 8 + j];
    aq[i] = f2bf(v);
  } else if (i < 98304) {
    int k2 = i - 65536;
    int j = k2 & 7;
    int l = (k2 >> 3) & 63;
    int t = (k2 >> 9) & 15;
    int h = k2 >> 13;
    int d = l & 15;
    int m = t * 32 + (l >> 4) * 8 + j;
    float v = (d < 8) ? mem[((size_t)h * MS_ + m) * 8 + d] : (d == 8 ? 1.0f : 0.0f);
    apv[k2] = f2bf(v);
  }
}

// ---------------- 1. NCHW -> NHWC transpose of x ----------------
__global__ void k_transpose(const float* __restrict__ x, float* __restrict__ x_hwc) {
  __shared__ float tile[C_][65];
  int blk = blockIdx.x;
  int b = blk >> 8;
  int n0 = (blk & 255) << 6;
  int t = threadIdx.x;
#pragma unroll
  for (int i = 0; i < 8; ++i) {
    int l = t + (i << 8);
    int c = l >> 6, p = l & 63;
    tile[c][p] = x[((size_t)(b * C_ + c)) * HW_ + n0 + p];
  }
  __syncthreads();
#pragma unroll
  for (int i = 0; i < 8; ++i) {
    int l = t + (i << 8);
    int p = l >> 5, c = l & 31;
    x_hwc[((size_t)b * HW_ + n0 + p) * C_ + c] = tile[c][p];
  }
}

// ---------------- 2. per-(b,c) spatial mean ----------------
__global__ void k_mean(const float* __restrict__ x, float* __restrict__ y_avg) {
  int bc = blockIdx.x;
  int t = threadIdx.x;
  const float* p = x + (size_t)bc * HW_;
  float s = 0.f;
  for (int i = t; i < HW_; i += 256) s += p[i];
  __shared__ float red[256];
  red[t] = s;
  __syncthreads();
  for (int off = 128; off > 0; off >>= 1) {
    if (t < off) red[t] += red[t + off];
    __syncthreads();
  }
  if (t == 0) y_avg[bc] = red[0] * (1.f / HW_);
}

// ---------------- 3. SE MLPs (tiny) ----------------
__global__ void k_se(const float* __restrict__ y_avg,
                     const float* __restrict__ fs_w1, const float* __restrict__ fs_w2,
                     const float* __restrict__ fc_w1, const float* __restrict__ fc_w2,
                     float* __restrict__ y_sp, float* __restrict__ y_ch) {
  int t = threadIdx.x;  // 128 = B*C
  int b = t >> 5, c = t & 31;
  const float* ya = y_avg + b * 32;
  {
    float h0 = 0.f, h1 = 0.f;
#pragma unroll
    for (int j = 0; j < 32; ++j) { h0 += ya[j] * fs_w1[j]; h1 += ya[j] * fs_w1[32 + j]; }
    h0 = fmaxf(h0, 0.f); h1 = fmaxf(h1, 0.f);
    float z = h0 * fs_w2[c * 2 + 0] + h1 * fs_w2[c * 2 + 1];
    y_sp[t] = 1.f / (1.f + __expf(-z));
  }
  {
    float hh[4];
#pragma unroll
    for (int jj = 0; jj < 4; ++jj) {
      float s = 0.f;
#pragma unroll
      for (int j = 0; j < 32; ++j) s += ya[j] * fc_w1[jj * 32 + j];
      hh[jj] = fmaxf(s, 0.f);
    }
    float z = 0.f;
#pragma unroll
    for (int jj = 0; jj < 4; ++jj) z += hh[jj] * fc_w2[c * 4 + jj];
    y_ch[t] = 1.f / (1.f + __expf(-z));
  }
}

// ---------------- 4. fused offset-conv + DCNv2 (unchanged from R3) ----
constexpr int TILE_F = 32 * 3 * 67;
constexpr int OUTP_F = 3 * 64 * 36;
constexpr int SHBUF_F = (TILE_F > OUTP_F ? TILE_F : OUTP_F);

__global__ __launch_bounds__(256, 4) void k_dcn(
    const float* __restrict__ x,
    const float* __restrict__ x_hwc,
    const float* __restrict__ off_wT, const float* __restrict__ off_b,
    const float* __restrict__ dcn_wT, const float* __restrict__ dcn_b,
    float* __restrict__ x3_hwc) {
  __shared__ float shbuf[SHBUF_F];
  __shared__ float om_lds[64][29];

  int blk = blockIdx.x;
  int b = blk >> 8;
  int rem = blk & 255;
  int y = rem >> 1;
  int x0 = (rem & 1) << 6;
  int t = threadIdx.x;
  int w = __builtin_amdgcn_readfirstlane(t >> 6);
  int pix = t & 63;

  for (int i = t; i < 32 * 3 * 66; i += 256) {
    int c = i / 198;
    int r2 = i - c * 198;
    int r = r2 / 66;
    int j = r2 - r * 66;
    int yy = y + r - 1;
    int xx = x0 - 1 + j;
    float v = (yy >= 0 && yy < H_ && xx >= 0 && xx < W_)
                  ? x[((size_t)(b * C_ + c)) * HW_ + yy * W_ + xx] : 0.f;
    shbuf[c * 201 + r * 67 + j] = v;
  }
  __syncthreads();

  int o0 = w * 7;
  int on = (w == 3) ? 6 : 7;
  {
    float om[7];
#pragma unroll
    for (int oi = 0; oi < 7; ++oi) om[oi] = (oi < on) ? off_b[o0 + oi] : 0.f;
    for (int c = 0; c < 32; ++c) {
      float v[9];
#pragma unroll
      for (int r = 0; r < 3; ++r)
#pragma unroll
        for (int dx = 0; dx < 3; ++dx)
          v[r * 3 + dx] = shbuf[c * 201 + r * 67 + pix + dx];
#pragma unroll
      for (int tap = 0; tap < 9; ++tap) {
        const float* wp = off_wT + (((size_t)(c * 9 + tap) * 4 + w) << 3);
        float4 w0 = *(const float4*)wp;
        float4 w1 = *(const float4*)(wp + 4);
        float vt = v[tap];
        om[0] += vt * w0.x; om[1] += vt * w0.y; om[2] += vt * w0.z; om[3] += vt * w0.w;
        om[4] += vt * w1.x; om[5] += vt * w1.y; om[6] += vt * w1.z;
      }
    }
    for (int oi = 0; oi < on; ++oi) om_lds[pix][o0 + oi] = om[oi];
  }
  __syncthreads();

  float omv[27];
#pragma unroll
  for (int o = 0; o < 27; ++o) omv[o] = om_lds[pix][o];

  float out[32];
#pragma unroll
  for (int o = 0; o < 32; ++o) out[o] = 0.f;

  const float* xb = x_hwc + (size_t)b * HW_ * C_;
  int c0 = w * 8;
  int px_i = x0 + pix;

  for (int k = 0; k < 9; ++k) {
    int ky = k / 3 - 1, kx = k % 3 - 1;
    float py = (float)(y + ky) + omv[2 * k];
    float px = (float)(px_i + kx) + omv[2 * k + 1];
    float y0f = floorf(py), x0f = floorf(px);
    float wy = py - y0f, wx = px - x0f;
    int yi0 = (int)y0f, xi0 = (int)x0f;
    float mask = 1.f / (1.f + __expf(-omv[18 + k]));

    float samp[8];
#pragma unroll
    for (int cc = 0; cc < 8; ++cc) samp[cc] = 0.f;

#pragma unroll
    for (int cy = 0; cy < 2; ++cy) {
      int yi = yi0 + cy;
      if (yi < 0 || yi >= H_) continue;
      float wgy = cy ? wy : 1.f - wy;
#pragma unroll
      for (int cx = 0; cx < 2; ++cx) {
        int xi = xi0 + cx;
        if (xi < 0 || xi >= W_) continue;
        float wgt = wgy * (cx ? wx : 1.f - wx);
        const float4* s4 = (const float4*)(xb + ((size_t)yi * W_ + xi) * C_ + c0);
        float4 a = s4[0], bb = s4[1];
        samp[0] += wgt * a.x;  samp[1] += wgt * a.y;
        samp[2] += wgt * a.z;  samp[3] += wgt * a.w;
        samp[4] += wgt * bb.x; samp[5] += wgt * bb.y;
        samp[6] += wgt * bb.z; samp[7] += wgt * bb.w;
      }
    }
#pragma unroll
    for (int cc = 0; cc < 8; ++cc) {
      float smc = samp[cc] * mask;
      const float4* wp4 = (const float4*)(dcn_wT + ((size_t)((c0 + cc) * 9 + k) << 5));
#pragma unroll
      for (int j = 0; j < 8; ++j) {
        float4 wv = wp4[j];
        out[4 * j + 0] += smc * wv.x;
        out[4 * j + 1] += smc * wv.y;
        out[4 * j + 2] += smc * wv.z;
        out[4 * j + 3] += smc * wv.w;
      }
    }
  }

  __syncthreads();
  if (w > 0) {
    float* op = shbuf + (w - 1) * 2304 + pix * 36;
#pragma unroll
    for (int o = 0; o < 32; o += 4) {
      float4 v4; v4.x = out[o]; v4.y = out[o + 1]; v4.z = out[o + 2]; v4.w = out[o + 3];
      *(float4*)(op + o) = v4;
    }
  }
  __syncthreads();
  if (w == 0) {
    const float* p0 = shbuf + pix * 36;
    float* dst = x3_hwc + ((size_t)b * HW_ + y * W_ + px_i) * C_;
#pragma unroll
    for (int o = 0; o < 32; o += 4) {
      float4 a = *(const float4*)(p0 + o);
      float4 b4 = *(const float4*)(p0 + 2304 + o);
      float4 c4 = *(const float4*)(p0 + 4608 + o);
      float4 v4;
      v4.x = out[o]     + a.x + b4.x + c4.x + dcn_b[o];
      v4.y = out[o + 1] + a.y + b4.y + c4.y + dcn_b[o + 1];
      v4.z = out[o + 2] + a.z + b4.z + c4.z + dcn_b[o + 2];
      v4.w = out[o + 3] + a.w + b4.w + c4.w + dcn_b[o + 3];
      *(float4*)(dst + o) = v4;
    }
  }
}

// ---------------- 5. fused switch + gating + MFMA memory attention --------
// Block = 256 thr = 4 waves over the SAME 64 pixels; wave g = head g.
// Phase A (switch): as R3; qv packed bf16*QSCALE -> qb_lds, fp32 xo -> xo_lds.
// Phase B: per 16-px tile: S^T = mfma(aq, q) (K=32, d-padded); exp2; P repacked
// via per-wave LDS bounce into PV B-frag; rec^T+= mfma(apv, P). apv row d=8 is
// ones => D row 8 = softmax denom. No barriers in phase B (per-wave LDS only).
__global__ __launch_bounds__(256, 4) void k_swattn(
    const float* __restrict__ x_hwc, const float* __restrict__ x3_hwc,
    const float* __restrict__ sw_w1, const float* __restrict__ sw_b1,
    const float* __restrict__ sw_w2, const float* __restrict__ sw_b2,
    const float* __restrict__ y_sp, const float* __restrict__ y_ch,
    const unsigned short* __restrict__ aq, const unsigned short* __restrict__ apv,
    float* __restrict__ out) {
  __shared__ float zbuf[2][4][64];
  __shared__ float xo_lds[4][64][9];
  __shared__ unsigned qb_lds[4][64][4];
  __shared__ unsigned long long pbuf[4][2][4][17];

  int t = threadIdx.x;
  int g = __builtin_amdgcn_readfirstlane(t >> 6);  // head id -> SGPR
  int p = t & 63;
  int pix0 = blockIdx.x * 64;
  int pix = pix0 + p;
  int b = pix >> 14;

  // ---- phase A: switch + gating (pixel-per-lane) ----
  float cat[64];
  {
    const float4* xa = (const float4*)(x_hwc + (size_t)pix * C_);
    const float4* xb = (const float4*)(x3_hwc + (size_t)pix * C_);
#pragma unroll
    for (int q = 0; q < 8; ++q) {
      float4 v = xa[q];
      cat[q * 4 + 0] = v.x; cat[q * 4 + 1] = v.y; cat[q * 4 + 2] = v.z; cat[q * 4 + 3] = v.w;
    }
#pragma unroll
    for (int q = 0; q < 8; ++q) {
      float4 v = xb[q];
      cat[32 + q * 4 + 0] = v.x; cat[32 + q * 4 + 1] = v.y; cat[32 + q * 4 + 2] = v.z; cat[32 + q * 4 + 3] = v.w;
    }
  }
  float zp0 = 0.f, zp1 = 0.f;
#pragma unroll
  for (int oi = 0; oi < 8; ++oi) {
    int o = g * 8 + oi;
    float s = sw_b1[o];
    const float* wp = sw_w1 + o * 64;
#pragma unroll
    for (int c2 = 0; c2 < 64; ++c2) s += cat[c2] * wp[c2];
    s = fmaxf(s, 0.f);
    zp0 += s * sw_w2[o];
    zp1 += s * sw_w2[32 + o];
  }
  zbuf[0][g][p] = zp0;
  zbuf[1][g][p] = zp1;
  __syncthreads();
  float z0 = zbuf[0][0][p] + zbuf[0][1][p] + zbuf[0][2][p] + zbuf[0][3][p] + sw_b2[0];
  float z1 = zbuf[1][0][p] + zbuf[1][1][p] + zbuf[1][2][p] + zbuf[1][3][p] + sw_b2[1];
  float s0 = 1.f / (1.f + __expf(-z0));
  float s1 = 1.f / (1.f + __expf(-z1));

  float qv[8];
  {
    const float4* qa = (const float4*)(x_hwc + (size_t)pix * C_ + g * 8);
    const float4* ga = (const float4*)(y_sp + b * 32 + g * 8);
    const float4* gc = (const float4*)(y_ch + b * 32 + g * 8);
    float4 a0 = qa[0], a1 = qa[1];
    float4 p0 = ga[0], p1 = ga[1];
    float4 c0 = gc[0], c1 = gc[1];
    qv[0] = a0.x + p0.x * s0 + c0.x * s1;
    qv[1] = a0.y + p0.y * s0 + c0.y * s1;
    qv[2] = a0.z + p0.z * s0 + c0.z * s1;
    qv[3] = a0.w + p0.w * s0 + c0.w * s1;
    qv[4] = a1.x + p1.x * s0 + c1.x * s1;
    qv[5] = a1.y + p1.y * s0 + c1.y * s1;
    qv[6] = a1.z + p1.z * s0 + c1.z * s1;
    qv[7] = a1.w + p1.w * s0 + c1.w * s1;
  }
#pragma unroll
  for (int d = 0; d < 8; ++d) xo_lds[g][p][d] = qv[d];
  {
    uint4 qp;
    qp.x = pk_bf16(qv[0] * QSCALE, qv[1] * QSCALE);
    qp.y = pk_bf16(qv[2] * QSCALE, qv[3] * QSCALE);
    qp.z = pk_bf16(qv[4] * QSCALE, qv[5] * QSCALE);
    qp.w = pk_bf16(qv[6] * QSCALE, qv[7] * QSCALE);
    *(uint4*)&qb_lds[g][p][0] = qp;
  }
  __syncthreads();   // qb/xo visibility within wave g (conservative)

  // ---- phase B: MFMA attention, wave g = head g ----
  int quar = (t >> 4) & 3;   // lane quarter
  int px = t & 15;           // pixel within 16-tile
  const uint4* aq4 = (const uint4*)aq;    // [h][t16][lane] 16B frags
  const uint4* apv4 = (const uint4*)apv;  // [h][t32][lane]
  int lane = t & 63;

  for (int T = 0; T < 4; ++T) {
    // B-frag of q for this pixel tile (lanes >=16 are zero: k=8..31 pad)
    uint4 qw = *(const uint4*)&qb_lds[g][T * 16 + px][0];
    if (lane >= 16) { qw.x = 0; qw.y = 0; qw.z = 0; qw.w = 0; }
    U4S8 bq; bq.u = qw;

    f32x4_t pv = {0.f, 0.f, 0.f, 0.f};

    for (int tt = 0; tt < 16; ++tt) {
      U4S8 a0, a1, av;
      a0.u = aq4[(g * 32 + 2 * tt) * 64 + lane];
      a1.u = aq4[(g * 32 + 2 * tt + 1) * 64 + lane];
      av.u = apv4[(g * 16 + tt) * 64 + lane];

      f32x4_t z4 = {0.f, 0.f, 0.f, 0.f};
      f32x4_t sA = __builtin_amdgcn_mfma_f32_16x16x32_bf16(a0.s, bq.s, z4, 0, 0, 0);
      f32x4_t sB = __builtin_amdgcn_mfma_f32_16x16x32_bf16(a1.s, bq.s, z4, 0, 0, 0);

      float pA0 = exp2f(sA[0]), pA1 = exp2f(sA[1]), pA2 = exp2f(sA[2]), pA3 = exp2f(sA[3]);
      float pB0 = exp2f(sB[0]), pB1 = exp2f(sB[1]), pB2 = exp2f(sB[2]), pB3 = exp2f(sB[3]);

      unsigned uA0 = pk_bf16(pA0, pA1), uA1 = pk_bf16(pA2, pA3);
      unsigned uB0 = pk_bf16(pB0, pB1), uB1 = pk_bf16(pB2, pB3);

      // per-wave P bounce: [s][srcquar][px] -> B-frag needs quar q reading
      // srcquar 2(q&1), 2(q&1)+1 of tile (q>>1)
      pbuf[g][0][quar][px] = ((unsigned long long)uA1 << 32) | uA0;
      pbuf[g][1][quar][px] = ((unsigned long long)uB1 << 32) | uB0;

      int sq = 2 * (quar & 1);
      int st = quar >> 1;
      unsigned long long r0 = pbuf[g][st][sq][px];
      unsigned long long r1 = pbuf[g][st][sq + 1][px];
      U4S8 bp;
      bp.u.x = (unsigned)r0; bp.u.y = (unsigned)(r0 >> 32);
      bp.u.z = (unsigned)r1; bp.u.w = (unsigned)(r1 >> 32);

      pv = __builtin_amdgcn_mfma_f32_16x16x32_bf16(av.s, bp.s, pv, 0, 0, 0);
    }

    // D: col=px, row=(quar)*4+r. rows 0-7 = rec (d), row 8 = softmax denom.
    float ls = __shfl(pv[0], 32 + px);   // lane 32+px holds row 8, col px
    float linv = 1.f / ls;
    if (quar < 2) {
      int n = (pix0 & (HW_ - 1)) + T * 16 + px;
#pragma unroll
      for (int r = 0; r < 4; ++r) {
        int d = quar * 4 + r;
        int c = g * 8 + d;
        float val = xo_lds[g][T * 16 + px][d] + pv[r] * linv;
        out[((size_t)(b * 32 + c)) * HW_ + n] = val;
      }
    }
  }
}

}  // namespace

extern "C" void kernel_launch(void* const* d_in, const int* in_sizes, int n_in,
                              void* d_out, int out_size, void* d_ws, size_t ws_size,
                              hipStream_t stream) {
  const float* x     = (const float*)d_in[0];
  const float* fs_w1 = (const float*)d_in[1];
  const float* fs_w2 = (const float*)d_in[2];
  const float* fc_w1 = (const float*)d_in[3];
  const float* fc_w2 = (const float*)d_in[4];
  const float* sw_w1 = (const float*)d_in[5];
  const float* sw_b1 = (const float*)d_in[6];
  const float* sw_w2 = (const float*)d_in[7];
  const float* sw_b2 = (const float*)d_in[8];
  const float* off_w = (const float*)d_in[9];
  const float* off_b = (const float*)d_in[10];
  const float* dcn_w = (const float*)d_in[11];
  const float* dcn_b = (const float*)d_in[12];
  const float* memw  = (const float*)d_in[13];
  float* out = (float*)d_out;

  float* ws = (float*)d_ws;
  float* y_avg  = ws;                 // 128
  float* y_sp   = ws + 128;           // 128
  float* y_ch   = ws + 256;           // 128
  float* x_hwc  = ws + 512;
  float* x3_hwc = x_hwc + (size_t)B_ * HW_ * C_;
  float* off_wT = x3_hwc + (size_t)B_ * HW_ * C_;  // 9216
  float* dcn_wT = off_wT + 9216;                   // 9216
  unsigned short* aq_buf  = (unsigned short*)(dcn_wT + 9216);  // 65536 bf16
  unsigned short* apv_buf = aq_buf + 65536;                    // 32768 bf16

  hipLaunchKernelGGL(k_prep, dim3(36), dim3(256), 0, stream, off_w, dcn_w, off_wT, dcn_wT);
  hipLaunchKernelGGL(k_prep_mem, dim3(384), dim3(256), 0, stream, memw, aq_buf, apv_buf);
  hipLaunchKernelGGL(k_transpose, dim3(B_ * 256), dim3(256), 0, stream, x, x_hwc);
  hipLaunchKernelGGL(k_mean, dim3(B_ * C_), dim3(256), 0, stream, x, y_avg);
  hipLaunchKernelGGL(k_se, dim3(1), dim3(128), 0, stream,
                     y_avg, fs_w1, fs_w2, fc_w1, fc_w2, y_sp, y_ch);
  hipLaunchKernelGGL(k_dcn, dim3(B_ * H_ * 2), dim3(256), 0, stream,
                     x, x_hwc, off_wT, off_b, dcn_wT, dcn_b, x3_hwc);
  hipLaunchKernelGGL(k_swattn, dim3(B_ * HW_ / 64), dim3(256), 0, stream,
                     x_hwc, x3_hwc, sw_w1, sw_b1, sw_w2, sw_b2, y_sp, y_ch,
                     aq_buf, apv_buf, out);
}

// Round 5
// 211.904 us; speedup vs baseline: 2.1641x; 1.1631x over previous
//
#include <hip/hip_runtime.h>
#include <hip/hip_bf16.h>

namespace {

constexpr int B_ = 4, C_ = 32, H_ = 128, W_ = 128;
constexpr int HW_ = H_ * W_;
constexpr int MS_ = 512;
// fold (1/sqrt(8)) * log2(e) into q so scores feed exp2 directly
#define QSCALE 0.5100975104f

typedef short bf16x8_t __attribute__((ext_vector_type(8)));
typedef float f32x4_t __attribute__((ext_vector_type(4)));

union U4S8 { uint4 u; bf16x8_t s; };
union BF2U { __hip_bfloat162 h; unsigned u; };

__device__ inline unsigned pk_bf16(float lo, float hi) {
  BF2U t; t.h = __float22bfloat162_rn(float2{lo, hi}); return t.u;
}
__device__ inline unsigned short f2bf(float f) {
  unsigned u = __float_as_uint(f);
  return (unsigned short)((u + 0x7FFF + ((u >> 16) & 1)) >> 16);
}

// ---------------- 0. prep: bake ALL MFMA A-fragments (bf16) ----------------
// Fragment layouts (m89-verified, reused from R4's passing attention):
//   A-frag: row = lane&15, K = (lane>>4)*8 + j
//   B-frag: col = lane&15, K = (lane>>4)*8 + j
//   D-frag: col = lane&15, row = (lane>>4)*4 + r
// aoff/adcn K-order: K = s*32 + c  (s = conv tap / dcn k; c = channel)
// aq  (A of S^T = mem x q^T): row m-slot, K=d (0-pad to 32)
// apv (A of rec^T = memT x P): row d (row 8 = ones -> softmax denom), K = m-slot
__global__ void k_prep_frags(const float* __restrict__ off_w, const float* __restrict__ dcn_w,
                             const float* __restrict__ mem,
                             unsigned short* __restrict__ aoff, unsigned short* __restrict__ adcn,
                             unsigned short* __restrict__ aq, unsigned short* __restrict__ apv) {
  int i = blockIdx.x * 256 + threadIdx.x;
  if (i < 9216) {
    int j = i & 7, l = (i >> 3) & 63, rest = i >> 9;
    int s = rest % 9, mt = rest / 9;
    int o = mt * 16 + (l & 15), c = (l >> 4) * 8 + j;
    aoff[i] = (o < 27) ? f2bf(off_w[((size_t)o * 32 + c) * 9 + s]) : (unsigned short)0;
  } else if (i < 18432) {
    int k = i - 9216;
    int j = k & 7, l = (k >> 3) & 63, rest = k >> 9;
    int s = rest % 9, mt = rest / 9;
    int o = mt * 16 + (l & 15), c = (l >> 4) * 8 + j;
    adcn[k] = f2bf(dcn_w[((size_t)o * 32 + c) * 9 + s]);
  } else if (i < 83968) {
    int k = i - 18432;
    int j = k & 7, l = (k >> 3) & 63, t = (k >> 9) & 31, h = k >> 14;
    float v = 0.f;
    if (l < 16) v = mem[((size_t)h * MS_ + t * 16 + l) * 8 + j];
    aq[k] = f2bf(v);
  } else if (i < 116736) {
    int k = i - 83968;
    int j = k & 7, l = (k >> 3) & 63, t = (k >> 9) & 15, h = k >> 13;
    int d = l & 15;
    int m = t * 32 + (l >> 4) * 8 + j;
    float v = (d < 8) ? mem[((size_t)h * MS_ + m) * 8 + d] : (d == 8 ? 1.0f : 0.0f);
    apv[k] = f2bf(v);
  }
}

// ---------------- 1. NCHW -> NHWC transpose of x ----------------
__global__ void k_transpose(const float* __restrict__ x, float* __restrict__ x_hwc) {
  __shared__ float tile[C_][65];
  int blk = blockIdx.x;
  int b = blk >> 8;
  int n0 = (blk & 255) << 6;
  int t = threadIdx.x;
#pragma unroll
  for (int i = 0; i < 8; ++i) {
    int l = t + (i << 8);
    int c = l >> 6, p = l & 63;
    tile[c][p] = x[((size_t)(b * C_ + c)) * HW_ + n0 + p];
  }
  __syncthreads();
#pragma unroll
  for (int i = 0; i < 8; ++i) {
    int l = t + (i << 8);
    int p = l >> 5, c = l & 31;
    x_hwc[((size_t)b * HW_ + n0 + p) * C_ + c] = tile[c][p];
  }
}

// ---------------- 2. per-(b,c) spatial mean ----------------
__global__ void k_mean(const float* __restrict__ x, float* __restrict__ y_avg) {
  int bc = blockIdx.x;
  int t = threadIdx.x;
  const float* p = x + (size_t)bc * HW_;
  float s = 0.f;
  for (int i = t; i < HW_; i += 256) s += p[i];
  __shared__ float red[256];
  red[t] = s;
  __syncthreads();
  for (int off = 128; off > 0; off >>= 1) {
    if (t < off) red[t] += red[t + off];
    __syncthreads();
  }
  if (t == 0) y_avg[bc] = red[0] * (1.f / HW_);
}

// ---------------- 3. SE MLPs (tiny) ----------------
__global__ void k_se(const float* __restrict__ y_avg,
                     const float* __restrict__ fs_w1, const float* __restrict__ fs_w2,
                     const float* __restrict__ fc_w1, const float* __restrict__ fc_w2,
                     float* __restrict__ y_sp, float* __restrict__ y_ch) {
  int t = threadIdx.x;  // 128 = B*C
  int b = t >> 5, c = t & 31;
  const float* ya = y_avg + b * 32;
  {
    float h0 = 0.f, h1 = 0.f;
#pragma unroll
    for (int j = 0; j < 32; ++j) { h0 += ya[j] * fs_w1[j]; h1 += ya[j] * fs_w1[32 + j]; }
    h0 = fmaxf(h0, 0.f); h1 = fmaxf(h1, 0.f);
    float z = h0 * fs_w2[c * 2 + 0] + h1 * fs_w2[c * 2 + 1];
    y_sp[t] = 1.f / (1.f + __expf(-z));
  }
  {
    float hh[4];
#pragma unroll
    for (int jj = 0; jj < 4; ++jj) {
      float s = 0.f;
#pragma unroll
      for (int j = 0; j < 32; ++j) s += ya[j] * fc_w1[jj * 32 + j];
      hh[jj] = fmaxf(s, 0.f);
    }
    float z = 0.f;
#pragma unroll
    for (int jj = 0; jj < 4; ++jj) z += hh[jj] * fc_w2[c * 4 + jj];
    y_ch[t] = 1.f / (1.f + __expf(-z));
  }
}

// ---------------- 4. full-MFMA offset-conv + DCNv2 ----------------
// Block = 256 thr = 4 waves; wave w owns 16 pixels [16w,16w+16) of a 64-px
// half-row. GEMM1: om(27xN) = off_w(27x288) x im2col, B-frag = 1 ds_read_b128
// from bf16 tile [pos][40] (channel-interleaved). om bounced via LDS to
// pixel-major. Sampling: lane (quar,px) gathers channels 8q..8q+8 of pixel px,
// packs bf16 -> IS the GEMM2 B-frag (K-order k*32+c). GEMM2 D + bias -> x3.
__global__ __launch_bounds__(256, 4) void k_dcn(
    const float* __restrict__ x,      // NCHW
    const float* __restrict__ x_hwc,  // (B,HW,C) fp32
    const unsigned short* __restrict__ aoff, const float* __restrict__ off_b,
    const unsigned short* __restrict__ adcn, const float* __restrict__ dcn_b,
    float* __restrict__ x3_hwc) {
  __shared__ __align__(16) unsigned short tile[198 * 40];  // [pos=r*66+j][c(+pad)]
  __shared__ __align__(16) float om_lds[64][28];

  int blk = blockIdx.x;
  int b = blk >> 8;
  int rem = blk & 255;
  int y = rem >> 1;
  int x0 = (rem & 1) << 6;
  int t = threadIdx.x;
  int w = t >> 6;
  int lane = t & 63;
  int quar = lane >> 4, px = lane & 15;
  int pxg = w * 16 + px;      // pixel within block [0,64)
  int xcol = x0 + pxg;        // global x coordinate of this lane's pixel

  // --- stage x tile (bf16): tile[(r*66+j)*40 + c] = x[b,c,y+r-1,x0-1+j] ---
  for (int i = t; i < 6336; i += 256) {
    int rc = i / 66;          // r*32 + c
    int j = i - rc * 66;
    int r = rc >> 5, c = rc & 31;
    int yy = y + r - 1;
    int xx = x0 - 1 + j;
    float v = (yy >= 0 && yy < H_ && xx >= 0 && xx < W_)
                  ? x[((size_t)(b * C_ + c)) * HW_ + yy * W_ + xx] : 0.f;
    tile[(r * 66 + j) * 40 + c] = f2bf(v);
  }
  __syncthreads();

  // --- GEMM1: offset conv via MFMA (K = tap*32 + c) ---
  const uint4* aoff4 = (const uint4*)aoff;
  f32x4_t acc0 = {0.f, 0.f, 0.f, 0.f}, acc1 = {0.f, 0.f, 0.f, 0.f};
#pragma unroll
  for (int s = 0; s < 9; ++s) {
    int r = s / 3, dx = s % 3;
    U4S8 a0, a1, bv;
    a0.u = aoff4[s * 64 + lane];
    a1.u = aoff4[(9 + s) * 64 + lane];
    bv.u = *(const uint4*)&tile[(r * 66 + pxg + dx) * 40 + quar * 8];
    acc0 = __builtin_amdgcn_mfma_f32_16x16x32_bf16(a0.s, bv.s, acc0, 0, 0, 0);
    acc1 = __builtin_amdgcn_mfma_f32_16x16x32_bf16(a1.s, bv.s, acc1, 0, 0, 0);
  }
  // bounce om D-frags (col=px,row=o) -> pixel-major om_lds[px][o], + bias
#pragma unroll
  for (int r = 0; r < 4; ++r) {
    int o = quar * 4 + r;
    om_lds[pxg][o] = acc0[r] + off_b[o];
  }
#pragma unroll
  for (int r = 0; r < 4; ++r) {
    int o = 16 + quar * 4 + r;
    if (o < 27) om_lds[pxg][o] = acc1[r] + off_b[o];
  }
  __syncthreads();

  // --- sampling + GEMM2 (K = k*32 + c); lane = (channels 8q..8q+8, pixel px) ---
  const uint4* adcn4 = (const uint4*)adcn;
  const float* xb = x_hwc + (size_t)b * HW_ * C_ + quar * 8;
  f32x4_t o0 = {0.f, 0.f, 0.f, 0.f}, o1 = {0.f, 0.f, 0.f, 0.f};
#pragma unroll
  for (int k = 0; k < 9; ++k) {
    int ky = k / 3 - 1, kx = k % 3 - 1;
    float py = (float)(y + ky) + om_lds[pxg][2 * k];
    float pxf = (float)(xcol + kx) + om_lds[pxg][2 * k + 1];
    float mask = 1.f / (1.f + __expf(-om_lds[pxg][18 + k]));
    float y0f = floorf(py), x0f = floorf(pxf);
    float wy = py - y0f, wx = pxf - x0f;
    int yi0 = (int)y0f, xi0 = (int)x0f;

    float samp[8];
#pragma unroll
    for (int cc = 0; cc < 8; ++cc) samp[cc] = 0.f;
#pragma unroll
    for (int cy = 0; cy < 2; ++cy) {
      int yi = yi0 + cy;
      if (yi < 0 || yi >= H_) continue;
      float wgy = cy ? wy : 1.f - wy;
#pragma unroll
      for (int cx = 0; cx < 2; ++cx) {
        int xi = xi0 + cx;
        if (xi < 0 || xi >= W_) continue;
        float wgt = wgy * (cx ? wx : 1.f - wx);
        const float4* s4 = (const float4*)(xb + ((size_t)yi * W_ + xi) * C_);
        float4 a = s4[0], bb = s4[1];
        samp[0] += wgt * a.x;  samp[1] += wgt * a.y;
        samp[2] += wgt * a.z;  samp[3] += wgt * a.w;
        samp[4] += wgt * bb.x; samp[5] += wgt * bb.y;
        samp[6] += wgt * bb.z; samp[7] += wgt * bb.w;
      }
    }
    U4S8 bs, a0, a1;
    bs.u.x = pk_bf16(samp[0] * mask, samp[1] * mask);
    bs.u.y = pk_bf16(samp[2] * mask, samp[3] * mask);
    bs.u.z = pk_bf16(samp[4] * mask, samp[5] * mask);
    bs.u.w = pk_bf16(samp[6] * mask, samp[7] * mask);
    a0.u = adcn4[k * 64 + lane];
    a1.u = adcn4[(9 + k) * 64 + lane];
    o0 = __builtin_amdgcn_mfma_f32_16x16x32_bf16(a0.s, bs.s, o0, 0, 0, 0);
    o1 = __builtin_amdgcn_mfma_f32_16x16x32_bf16(a1.s, bs.s, o1, 0, 0, 0);
  }

  // --- epilogue: D (col=px,row=o) + bias -> x3_hwc ---
  float4 db0 = *(const float4*)(dcn_b + quar * 4);
  float4 db1 = *(const float4*)(dcn_b + 16 + quar * 4);
  float* dst = x3_hwc + ((size_t)b * HW_ + y * W_ + xcol) * C_;
  dst[quar * 4 + 0] = o0[0] + db0.x;
  dst[quar * 4 + 1] = o0[1] + db0.y;
  dst[quar * 4 + 2] = o0[2] + db0.z;
  dst[quar * 4 + 3] = o0[3] + db0.w;
  dst[16 + quar * 4 + 0] = o1[0] + db1.x;
  dst[16 + quar * 4 + 1] = o1[1] + db1.y;
  dst[16 + quar * 4 + 2] = o1[2] + db1.z;
  dst[16 + quar * 4 + 3] = o1[3] + db1.w;
}

// ---------------- 5. fused switch + gating + MFMA memory attention --------
// As R4 (verified) but hoisted: tt-outer / pixel-tile-inner so each aq/apv
// fragment is loaded once (4x fewer VMEM; loads overlap 12 MFMAs per tt).
__global__ __launch_bounds__(256, 4) void k_swattn(
    const float* __restrict__ x_hwc, const float* __restrict__ x3_hwc,
    const float* __restrict__ sw_w1, const float* __restrict__ sw_b1,
    const float* __restrict__ sw_w2, const float* __restrict__ sw_b2,
    const float* __restrict__ y_sp, const float* __restrict__ y_ch,
    const unsigned short* __restrict__ aq, const unsigned short* __restrict__ apv,
    float* __restrict__ out) {
  __shared__ float zbuf[2][4][64];
  __shared__ float xo_lds[4][64][9];
  __shared__ __align__(16) unsigned qb_lds[4][64][4];
  __shared__ unsigned long long pbuf[4][2][4][17];

  int t = threadIdx.x;
  int g = __builtin_amdgcn_readfirstlane(t >> 6);  // head id -> SGPR
  int p = t & 63;
  int pix0 = blockIdx.x * 64;
  int pix = pix0 + p;
  int b = pix >> 14;

  // ---- phase A: switch + gating (pixel-per-lane) ----
  float cat[64];
  {
    const float4* xa = (const float4*)(x_hwc + (size_t)pix * C_);
    const float4* xb = (const float4*)(x3_hwc + (size_t)pix * C_);
#pragma unroll
    for (int q = 0; q < 8; ++q) {
      float4 v = xa[q];
      cat[q * 4 + 0] = v.x; cat[q * 4 + 1] = v.y; cat[q * 4 + 2] = v.z; cat[q * 4 + 3] = v.w;
    }
#pragma unroll
    for (int q = 0; q < 8; ++q) {
      float4 v = xb[q];
      cat[32 + q * 4 + 0] = v.x; cat[32 + q * 4 + 1] = v.y; cat[32 + q * 4 + 2] = v.z; cat[32 + q * 4 + 3] = v.w;
    }
  }
  float zp0 = 0.f, zp1 = 0.f;
#pragma unroll
  for (int oi = 0; oi < 8; ++oi) {
    int o = g * 8 + oi;
    float s = sw_b1[o];
    const float* wp = sw_w1 + o * 64;
#pragma unroll
    for (int c2 = 0; c2 < 64; ++c2) s += cat[c2] * wp[c2];
    s = fmaxf(s, 0.f);
    zp0 += s * sw_w2[o];
    zp1 += s * sw_w2[32 + o];
  }
  zbuf[0][g][p] = zp0;
  zbuf[1][g][p] = zp1;
  __syncthreads();
  float z0 = zbuf[0][0][p] + zbuf[0][1][p] + zbuf[0][2][p] + zbuf[0][3][p] + sw_b2[0];
  float z1 = zbuf[1][0][p] + zbuf[1][1][p] + zbuf[1][2][p] + zbuf[1][3][p] + sw_b2[1];
  float s0 = 1.f / (1.f + __expf(-z0));
  float s1 = 1.f / (1.f + __expf(-z1));

  float qv[8];
  {
    const float4* qa = (const float4*)(x_hwc + (size_t)pix * C_ + g * 8);
    const float4* ga = (const float4*)(y_sp + b * 32 + g * 8);
    const float4* gc = (const float4*)(y_ch + b * 32 + g * 8);
    float4 a0 = qa[0], a1 = qa[1];
    float4 p0 = ga[0], p1 = ga[1];
    float4 c0 = gc[0], c1 = gc[1];
    qv[0] = a0.x + p0.x * s0 + c0.x * s1;
    qv[1] = a0.y + p0.y * s0 + c0.y * s1;
    qv[2] = a0.z + p0.z * s0 + c0.z * s1;
    qv[3] = a0.w + p0.w * s0 + c0.w * s1;
    qv[4] = a1.x + p1.x * s0 + c1.x * s1;
    qv[5] = a1.y + p1.y * s0 + c1.y * s1;
    qv[6] = a1.z + p1.z * s0 + c1.z * s1;
    qv[7] = a1.w + p1.w * s0 + c1.w * s1;
  }
#pragma unroll
  for (int d = 0; d < 8; ++d) xo_lds[g][p][d] = qv[d];
  {
    uint4 qp;
    qp.x = pk_bf16(qv[0] * QSCALE, qv[1] * QSCALE);
    qp.y = pk_bf16(qv[2] * QSCALE, qv[3] * QSCALE);
    qp.z = pk_bf16(qv[4] * QSCALE, qv[5] * QSCALE);
    qp.w = pk_bf16(qv[6] * QSCALE, qv[7] * QSCALE);
    *(uint4*)&qb_lds[g][p][0] = qp;
  }
  // no barrier: qb_lds[g]/xo_lds[g] are written and read by wave g only

  // ---- phase B: MFMA attention, wave g = head g, hoisted fragments ----
  int quar = (t >> 4) & 3;
  int px = t & 15;
  int lane = t & 63;
  const uint4* aq4 = (const uint4*)aq;
  const uint4* apv4 = (const uint4*)apv;

  U4S8 bq[4];
#pragma unroll
  for (int T = 0; T < 4; ++T) {
    uint4 qw = *(const uint4*)&qb_lds[g][T * 16 + px][0];
    if (lane >= 16) { qw.x = 0; qw.y = 0; qw.z = 0; qw.w = 0; }
    bq[T].u = qw;
  }
  f32x4_t pv[4];
#pragma unroll
  for (int T = 0; T < 4; ++T) pv[T] = f32x4_t{0.f, 0.f, 0.f, 0.f};

  for (int tt = 0; tt < 16; ++tt) {
    U4S8 a0, a1, av;
    a0.u = aq4[(g * 32 + 2 * tt) * 64 + lane];
    a1.u = aq4[(g * 32 + 2 * tt + 1) * 64 + lane];
    av.u = apv4[(g * 16 + tt) * 64 + lane];
    f32x4_t z4 = {0.f, 0.f, 0.f, 0.f};
#pragma unroll
    for (int T = 0; T < 4; ++T) {
      f32x4_t sA = __builtin_amdgcn_mfma_f32_16x16x32_bf16(a0.s, bq[T].s, z4, 0, 0, 0);
      f32x4_t sB = __builtin_amdgcn_mfma_f32_16x16x32_bf16(a1.s, bq[T].s, z4, 0, 0, 0);
      unsigned uA0 = pk_bf16(exp2f(sA[0]), exp2f(sA[1]));
      unsigned uA1 = pk_bf16(exp2f(sA[2]), exp2f(sA[3]));
      unsigned uB0 = pk_bf16(exp2f(sB[0]), exp2f(sB[1]));
      unsigned uB1 = pk_bf16(exp2f(sB[2]), exp2f(sB[3]));
      pbuf[g][0][quar][px] = ((unsigned long long)uA1 << 32) | uA0;
      pbuf[g][1][quar][px] = ((unsigned long long)uB1 << 32) | uB0;
      int sq = 2 * (quar & 1);
      int st = quar >> 1;
      unsigned long long r0 = pbuf[g][st][sq][px];
      unsigned long long r1 = pbuf[g][st][sq + 1][px];
      U4S8 bp;
      bp.u.x = (unsigned)r0; bp.u.y = (unsigned)(r0 >> 32);
      bp.u.z = (unsigned)r1; bp.u.w = (unsigned)(r1 >> 32);
      pv[T] = __builtin_amdgcn_mfma_f32_16x16x32_bf16(av.s, bp.s, pv[T], 0, 0, 0);
    }
  }

#pragma unroll
  for (int T = 0; T < 4; ++T) {
    float ls = __shfl(pv[T][0], 32 + px);   // row 8 (ones-row) = softmax denom
    float linv = 1.f / ls;
    if (quar < 2) {
      int n = (pix0 & (HW_ - 1)) + T * 16 + px;
#pragma unroll
      for (int r = 0; r < 4; ++r) {
        int d = quar * 4 + r;
        int c = g * 8 + d;
        float val = xo_lds[g][T * 16 + px][d] + pv[T][r] * linv;
        out[((size_t)(b * 32 + c)) * HW_ + n] = val;
      }
    }
  }
}

}  // namespace

extern "C" void kernel_launch(void* const* d_in, const int* in_sizes, int n_in,
                              void* d_out, int out_size, void* d_ws, size_t ws_size,
                              hipStream_t stream) {
  const float* x     = (const float*)d_in[0];
  const float* fs_w1 = (const float*)d_in[1];
  const float* fs_w2 = (const float*)d_in[2];
  const float* fc_w1 = (const float*)d_in[3];
  const float* fc_w2 = (const float*)d_in[4];
  const float* sw_w1 = (const float*)d_in[5];
  const float* sw_b1 = (const float*)d_in[6];
  const float* sw_w2 = (const float*)d_in[7];
  const float* sw_b2 = (const float*)d_in[8];
  const float* off_w = (const float*)d_in[9];
  const float* off_b = (const float*)d_in[10];
  const float* dcn_w = (const float*)d_in[11];
  const float* dcn_b = (const float*)d_in[12];
  const float* memw  = (const float*)d_in[13];
  float* out = (float*)d_out;

  float* ws = (float*)d_ws;
  float* y_avg  = ws;                 // 128
  float* y_sp   = ws + 128;           // 128
  float* y_ch   = ws + 256;           // 128
  float* x_hwc  = ws + 512;
  float* x3_hwc = x_hwc + (size_t)B_ * HW_ * C_;
  unsigned short* aoff_buf = (unsigned short*)(x3_hwc + (size_t)B_ * HW_ * C_);
  unsigned short* adcn_buf = aoff_buf + 9216;
  unsigned short* aq_buf   = adcn_buf + 9216;   // 65536 bf16
  unsigned short* apv_buf  = aq_buf + 65536;    // 32768 bf16

  hipLaunchKernelGGL(k_prep_frags, dim3(456), dim3(256), 0, stream,
                     off_w, dcn_w, memw, aoff_buf, adcn_buf, aq_buf, apv_buf);
  hipLaunchKernelGGL(k_transpose, dim3(B_ * 256), dim3(256), 0, stream, x, x_hwc);
  hipLaunchKernelGGL(k_mean, dim3(B_ * C_), dim3(256), 0, stream, x, y_avg);
  hipLaunchKernelGGL(k_se, dim3(1), dim3(128), 0, stream,
                     y_avg, fs_w1, fs_w2, fc_w1, fc_w2, y_sp, y_ch);
  hipLaunchKernelGGL(k_dcn, dim3(B_ * H_ * 2), dim3(256), 0, stream,
                     x, x_hwc, aoff_buf, off_b, adcn_buf, dcn_b, x3_hwc);
  hipLaunchKernelGGL(k_swattn, dim3(B_ * HW_ / 64), dim3(256), 0, stream,
                     x_hwc, x3_hwc, sw_w1, sw_b1, sw_w2, sw_b2, y_sp, y_ch,
                     aq_buf, apv_buf, out);
}

// Round 6
// 196.624 us; speedup vs baseline: 2.3323x; 1.0777x over previous
//
#include <hip/hip_runtime.h>
#include <hip/hip_bf16.h>

namespace {

constexpr int B_ = 4, C_ = 32, H_ = 128, W_ = 128;
constexpr int HW_ = H_ * W_;
constexpr int MS_ = 512;
// fold (1/sqrt(8)) * log2(e) into q so scores feed exp2 directly
#define QSCALE 0.5100975104f

typedef short bf16x8_t __attribute__((ext_vector_type(8)));
typedef float f32x4_t __attribute__((ext_vector_type(4)));
typedef float f32x16_t __attribute__((ext_vector_type(16)));

union U4S8 { uint4 u; bf16x8_t s; };
union BF2U { __hip_bfloat162 h; unsigned u; };

__device__ inline unsigned pk_bf16(float lo, float hi) {
  BF2U t; t.h = __float22bfloat162_rn(float2{lo, hi}); return t.u;
}
__device__ inline unsigned short f2bf(float f) {
  unsigned u = __float_as_uint(f);
  return (unsigned short)((u + 0x7FFF + ((u >> 16) & 1)) >> 16);
}

// ---------------- 0. prep: bake ALL MFMA A-fragments (bf16) ----------------
// 16x16x32 frags (aoff, adcn): A row=lane&15, K=(lane>>4)*8+j
// 32x32x16 frags (aq32, apv32): A row=lane&31, K=(lane>>5)*8+j
// asw (16x16x32, switch conv): row = half*16+(lane&15), K = kstep*32+(lane>>4)*8+j
__global__ void k_prep_frags(const float* __restrict__ off_w, const float* __restrict__ dcn_w,
                             const float* __restrict__ mem, const float* __restrict__ sw_w1,
                             unsigned short* __restrict__ aoff, unsigned short* __restrict__ adcn,
                             unsigned short* __restrict__ aq32, unsigned short* __restrict__ apv32,
                             unsigned short* __restrict__ asw) {
  int i = blockIdx.x * 256 + threadIdx.x;
  if (i < 9216) {
    int j = i & 7, l = (i >> 3) & 63, rest = i >> 9;
    int s = rest % 9, mt = rest / 9;
    int o = mt * 16 + (l & 15), c = (l >> 4) * 8 + j;
    aoff[i] = (o < 27) ? f2bf(off_w[((size_t)o * 32 + c) * 9 + s]) : (unsigned short)0;
  } else if (i < 18432) {
    int k = i - 9216;
    int j = k & 7, l = (k >> 3) & 63, rest = k >> 9;
    int s = rest % 9, mt = rest / 9;
    int o = mt * 16 + (l & 15), c = (l >> 4) * 8 + j;
    adcn[k] = f2bf(dcn_w[((size_t)o * 32 + c) * 9 + s]);
  } else if (i < 51200) {
    // aq32[h][t32][lane][j]: A of S = mem(32 slots x K16: d 0..7 | pad)
    int k = i - 18432;
    int j = k & 7, l = (k >> 3) & 63, t32 = (k >> 9) & 15, h = k >> 13;
    int slot = t32 * 32 + (l & 31);
    aq32[k] = (l < 32) ? f2bf(mem[((size_t)h * MS_ + slot) * 8 + j]) : (unsigned short)0;
  } else if (i < 116736) {
    // apv32[h][t32][grp][lane][j]: A of rec^T; rows: d 0..7, row8 = ones (denom)
    int k = i - 51200;
    int j = k & 7, l = (k >> 3) & 63, grp = (k >> 9) & 1, t32 = (k >> 10) & 15, h = k >> 14;
    int row = l & 31;
    int slot = t32 * 32 + grp * 16 + (l >> 5) * 8 + j;
    float v = (row < 8) ? mem[((size_t)h * MS_ + slot) * 8 + row] : (row == 8 ? 1.0f : 0.0f);
    apv32[k] = f2bf(v);
  } else if (i < 118784) {
    // asw[kstep][half][lane][j]
    int k = i - 116736;
    int j = k & 7, l = (k >> 3) & 63, half = (k >> 9) & 1, kstep = (k >> 10) & 1;
    int o = half * 16 + (l & 15);
    int catc = kstep * 32 + (l >> 4) * 8 + j;
    asw[k] = f2bf(sw_w1[(size_t)o * 64 + catc]);
  }
}

// ---------------- 1. NCHW -> NHWC transpose of x (+ fused mean partials) ----
__global__ void k_transpose(const float* __restrict__ x, float* __restrict__ x_hwc,
                            float* __restrict__ y_sum) {
  __shared__ float tile[C_][65];
  int blk = blockIdx.x;
  int b = blk >> 8;
  int n0 = (blk & 255) << 6;
  int t = threadIdx.x;
#pragma unroll
  for (int i = 0; i < 8; ++i) {
    int l = t + (i << 8);
    int c = l >> 6, p = l & 63;
    tile[c][p] = x[((size_t)(b * C_ + c)) * HW_ + n0 + p];
  }
  __syncthreads();
#pragma unroll
  for (int i = 0; i < 8; ++i) {
    int l = t + (i << 8);
    int p = l >> 5, c = l & 31;
    x_hwc[((size_t)b * HW_ + n0 + p) * C_ + c] = tile[c][p];
  }
  // fused mean partial: thread (c = t>>3, i = t&7) sums 8 px, 8-lane reduce
  int c = t >> 3, ii = t & 7;
  float s = 0.f;
#pragma unroll
  for (int k = 0; k < 8; ++k) s += tile[c][ii * 8 + k];
  s += __shfl_xor(s, 1);
  s += __shfl_xor(s, 2);
  s += __shfl_xor(s, 4);
  if (ii == 0) atomicAdd(&y_sum[b * 32 + c], s);
}

// ---------------- 3. SE MLPs (tiny) ----------------
__global__ void k_se(const float* __restrict__ y_sum,
                     const float* __restrict__ fs_w1, const float* __restrict__ fs_w2,
                     const float* __restrict__ fc_w1, const float* __restrict__ fc_w2,
                     float* __restrict__ y_sp, float* __restrict__ y_ch) {
  int t = threadIdx.x;  // 128 = B*C
  int b = t >> 5, c = t & 31;
  float ya[32];
#pragma unroll
  for (int j = 0; j < 32; ++j) ya[j] = y_sum[b * 32 + j] * (1.f / HW_);
  {
    float h0 = 0.f, h1 = 0.f;
#pragma unroll
    for (int j = 0; j < 32; ++j) { h0 += ya[j] * fs_w1[j]; h1 += ya[j] * fs_w1[32 + j]; }
    h0 = fmaxf(h0, 0.f); h1 = fmaxf(h1, 0.f);
    float z = h0 * fs_w2[c * 2 + 0] + h1 * fs_w2[c * 2 + 1];
    y_sp[t] = 1.f / (1.f + __expf(-z));
  }
  {
    float hh[4];
#pragma unroll
    for (int jj = 0; jj < 4; ++jj) {
      float s = 0.f;
#pragma unroll
      for (int j = 0; j < 32; ++j) s += ya[j] * fc_w1[jj * 32 + j];
      hh[jj] = fmaxf(s, 0.f);
    }
    float z = 0.f;
#pragma unroll
    for (int jj = 0; jj < 4; ++jj) z += hh[jj] * fc_w2[c * 4 + jj];
    y_ch[t] = 1.f / (1.f + __expf(-z));
  }
}

// ---------------- 4. full-MFMA offset-conv + DCNv2 (unchanged from R5) ------
__global__ __launch_bounds__(256, 4) void k_dcn(
    const float* __restrict__ x,      // NCHW
    const float* __restrict__ x_hwc,  // (B,HW,C) fp32
    const unsigned short* __restrict__ aoff, const float* __restrict__ off_b,
    const unsigned short* __restrict__ adcn, const float* __restrict__ dcn_b,
    float* __restrict__ x3_hwc) {
  __shared__ __align__(16) unsigned short tile[198 * 40];
  __shared__ __align__(16) float om_lds[64][28];

  int blk = blockIdx.x;
  int b = blk >> 8;
  int rem = blk & 255;
  int y = rem >> 1;
  int x0 = (rem & 1) << 6;
  int t = threadIdx.x;
  int w = t >> 6;
  int lane = t & 63;
  int quar = lane >> 4, px = lane & 15;
  int pxg = w * 16 + px;
  int xcol = x0 + pxg;

  for (int i = t; i < 6336; i += 256) {
    int rc = i / 66;
    int j = i - rc * 66;
    int r = rc >> 5, c = rc & 31;
    int yy = y + r - 1;
    int xx = x0 - 1 + j;
    float v = (yy >= 0 && yy < H_ && xx >= 0 && xx < W_)
                  ? x[((size_t)(b * C_ + c)) * HW_ + yy * W_ + xx] : 0.f;
    tile[(r * 66 + j) * 40 + c] = f2bf(v);
  }
  __syncthreads();

  const uint4* aoff4 = (const uint4*)aoff;
  f32x4_t acc0 = {0.f, 0.f, 0.f, 0.f}, acc1 = {0.f, 0.f, 0.f, 0.f};
#pragma unroll
  for (int s = 0; s < 9; ++s) {
    int r = s / 3, dx = s % 3;
    U4S8 a0, a1, bv;
    a0.u = aoff4[s * 64 + lane];
    a1.u = aoff4[(9 + s) * 64 + lane];
    bv.u = *(const uint4*)&tile[(r * 66 + pxg + dx) * 40 + quar * 8];
    acc0 = __builtin_amdgcn_mfma_f32_16x16x32_bf16(a0.s, bv.s, acc0, 0, 0, 0);
    acc1 = __builtin_amdgcn_mfma_f32_16x16x32_bf16(a1.s, bv.s, acc1, 0, 0, 0);
  }
#pragma unroll
  for (int r = 0; r < 4; ++r) {
    int o = quar * 4 + r;
    om_lds[pxg][o] = acc0[r] + off_b[o];
  }
#pragma unroll
  for (int r = 0; r < 4; ++r) {
    int o = 16 + quar * 4 + r;
    if (o < 27) om_lds[pxg][o] = acc1[r] + off_b[o];
  }
  __syncthreads();

  const uint4* adcn4 = (const uint4*)adcn;
  const float* xb = x_hwc + (size_t)b * HW_ * C_ + quar * 8;
  f32x4_t o0 = {0.f, 0.f, 0.f, 0.f}, o1 = {0.f, 0.f, 0.f, 0.f};
#pragma unroll
  for (int k = 0; k < 9; ++k) {
    int ky = k / 3 - 1, kx = k % 3 - 1;
    float py = (float)(y + ky) + om_lds[pxg][2 * k];
    float pxf = (float)(xcol + kx) + om_lds[pxg][2 * k + 1];
    float mask = 1.f / (1.f + __expf(-om_lds[pxg][18 + k]));
    float y0f = floorf(py), x0f = floorf(pxf);
    float wy = py - y0f, wx = pxf - x0f;
    int yi0 = (int)y0f, xi0 = (int)x0f;

    float samp[8];
#pragma unroll
    for (int cc = 0; cc < 8; ++cc) samp[cc] = 0.f;
#pragma unroll
    for (int cy = 0; cy < 2; ++cy) {
      int yi = yi0 + cy;
      if (yi < 0 || yi >= H_) continue;
      float wgy = cy ? wy : 1.f - wy;
#pragma unroll
      for (int cx = 0; cx < 2; ++cx) {
        int xi = xi0 + cx;
        if (xi < 0 || xi >= W_) continue;
        float wgt = wgy * (cx ? wx : 1.f - wx);
        const float4* s4 = (const float4*)(xb + ((size_t)yi * W_ + xi) * C_);
        float4 a = s4[0], bb = s4[1];
        samp[0] += wgt * a.x;  samp[1] += wgt * a.y;
        samp[2] += wgt * a.z;  samp[3] += wgt * a.w;
        samp[4] += wgt * bb.x; samp[5] += wgt * bb.y;
        samp[6] += wgt * bb.z; samp[7] += wgt * bb.w;
      }
    }
    U4S8 bs, a0, a1;
    bs.u.x = pk_bf16(samp[0] * mask, samp[1] * mask);
    bs.u.y = pk_bf16(samp[2] * mask, samp[3] * mask);
    bs.u.z = pk_bf16(samp[4] * mask, samp[5] * mask);
    bs.u.w = pk_bf16(samp[6] * mask, samp[7] * mask);
    a0.u = adcn4[k * 64 + lane];
    a1.u = adcn4[(9 + k) * 64 + lane];
    o0 = __builtin_amdgcn_mfma_f32_16x16x32_bf16(a0.s, bs.s, o0, 0, 0, 0);
    o1 = __builtin_amdgcn_mfma_f32_16x16x32_bf16(a1.s, bs.s, o1, 0, 0, 0);
  }

  float4 db0 = *(const float4*)(dcn_b + quar * 4);
  float4 db1 = *(const float4*)(dcn_b + 16 + quar * 4);
  float* dst = x3_hwc + ((size_t)b * HW_ + y * W_ + xcol) * C_;
  dst[quar * 4 + 0] = o0[0] + db0.x;
  dst[quar * 4 + 1] = o0[1] + db0.y;
  dst[quar * 4 + 2] = o0[2] + db0.z;
  dst[quar * 4 + 3] = o0[3] + db0.w;
  dst[16 + quar * 4 + 0] = o1[0] + db1.x;
  dst[16 + quar * 4 + 1] = o1[1] + db1.y;
  dst[16 + quar * 4 + 2] = o1[2] + db1.z;
  dst[16 + quar * 4 + 3] = o1[3] + db1.w;
}

// ---------------- 5. fused switch + gating + 32x32-MFMA attention ----------
// Phase A: wave w owns 16 px; h1 = 4 MFMAs (B-frag = own packed x/x3 slice);
// z via shfl_xor(16/32); lane (quar,px) owns xo channels 8quar..+8 = head
// quar's q slice -> writes qb_lds/xo_lds. ONE barrier.
// Phase B: wave g = head g over 64 px (2 tiles of 32). Per 32-slot tile:
// 1 score MFMA (32x32x16) -> 16 exp2 -> 8 cvt_pk -> 4 permlane32_swap -> 2 PV
// MFMAs. Register-only repack, zero LDS in inner loop. apv row 8 = ones
// => pv reg4 (low half) = softmax denom.
__device__ inline void attn_step(const bf16x8_t aqf, const bf16x8_t ap0, const bf16x8_t ap1,
                                 const bf16x8_t bq, f32x16_t& acc) {
  f32x16_t zz = {0.f,0.f,0.f,0.f,0.f,0.f,0.f,0.f,0.f,0.f,0.f,0.f,0.f,0.f,0.f,0.f};
  f32x16_t d = __builtin_amdgcn_mfma_f32_32x32x16_bf16(aqf, bq, zz, 0, 0, 0);
  unsigned w[8];
#pragma unroll
  for (int v = 0; v < 8; ++v) w[v] = pk_bf16(exp2f(d[2 * v]), exp2f(d[2 * v + 1]));
  // vdst.lo <-> vsrc.hi: swap(w2,w0) yields BOTH B-frag words v2 (=w2') and v0 (=w0')
  asm("v_permlane32_swap_b32 %0, %1" : "+v"(w[2]), "+v"(w[0]));
  asm("v_permlane32_swap_b32 %0, %1" : "+v"(w[3]), "+v"(w[1]));
  asm("v_permlane32_swap_b32 %0, %1" : "+v"(w[6]), "+v"(w[4]));
  asm("v_permlane32_swap_b32 %0, %1" : "+v"(w[7]), "+v"(w[5]));
  U4S8 f1, f2;
  f1.u.x = w[0]; f1.u.y = w[1]; f1.u.z = w[2]; f1.u.w = w[3];
  f2.u.x = w[4]; f2.u.y = w[5]; f2.u.z = w[6]; f2.u.w = w[7];
  acc = __builtin_amdgcn_mfma_f32_32x32x16_bf16(ap0, f1.s, acc, 0, 0, 0);
  acc = __builtin_amdgcn_mfma_f32_32x32x16_bf16(ap1, f2.s, acc, 0, 0, 0);
}

__global__ __launch_bounds__(256, 2) void k_swattn(
    const float* __restrict__ x_hwc, const float* __restrict__ x3_hwc,
    const unsigned short* __restrict__ asw, const float* __restrict__ sw_b1,
    const float* __restrict__ sw_w2, const float* __restrict__ sw_b2,
    const float* __restrict__ y_sp, const float* __restrict__ y_ch,
    const unsigned short* __restrict__ aq32, const unsigned short* __restrict__ apv32,
    float* __restrict__ out) {
  __shared__ float xo_lds[4][65][9];       // [head][pixel][d] (pad: bank spread)
  __shared__ __align__(16) unsigned qb_lds[4][65][4];  // packed bf16 q * QSCALE

  int t = threadIdx.x;
  int wv = __builtin_amdgcn_readfirstlane(t >> 6);
  int lane = t & 63;
  int quar = lane >> 4, px16 = lane & 15;
  int pix0 = blockIdx.x * 64;
  int b = blockIdx.x >> 8;
  int nbase = pix0 & (HW_ - 1);

  // ---- phase A: switch conv via MFMA; wave wv owns pixels [16wv,16wv+16) ----
  int pA = wv * 16 + px16;
  int pix = pix0 + pA;
  const float* xp  = x_hwc  + (size_t)pix * C_ + quar * 8;
  const float* x3p = x3_hwc + (size_t)pix * C_ + quar * 8;
  float4 xa0 = ((const float4*)xp)[0],  xa1 = ((const float4*)xp)[1];
  float4 x30 = ((const float4*)x3p)[0], x31 = ((const float4*)x3p)[1];
  U4S8 bx, bx3;
  bx.u.x  = pk_bf16(xa0.x, xa0.y); bx.u.y  = pk_bf16(xa0.z, xa0.w);
  bx.u.z  = pk_bf16(xa1.x, xa1.y); bx.u.w  = pk_bf16(xa1.z, xa1.w);
  bx3.u.x = pk_bf16(x30.x, x30.y); bx3.u.y = pk_bf16(x30.z, x30.w);
  bx3.u.z = pk_bf16(x31.x, x31.y); bx3.u.w = pk_bf16(x31.z, x31.w);

  const uint4* asw4 = (const uint4*)asw;
  U4S8 a00, a01, a10, a11;
  a00.u = asw4[0 * 64 + lane];  // kstep0 half0
  a01.u = asw4[1 * 64 + lane];  // kstep0 half1
  a10.u = asw4[2 * 64 + lane];  // kstep1 half0
  a11.u = asw4[3 * 64 + lane];  // kstep1 half1
  f32x4_t z4 = {0.f, 0.f, 0.f, 0.f};
  f32x4_t hlo = __builtin_amdgcn_mfma_f32_16x16x32_bf16(a00.s, bx.s, z4, 0, 0, 0);
  hlo = __builtin_amdgcn_mfma_f32_16x16x32_bf16(a10.s, bx3.s, hlo, 0, 0, 0);
  f32x4_t hhi = __builtin_amdgcn_mfma_f32_16x16x32_bf16(a01.s, bx.s, z4, 0, 0, 0);
  hhi = __builtin_amdgcn_mfma_f32_16x16x32_bf16(a11.s, bx3.s, hhi, 0, 0, 0);

  float4 b1lo = *(const float4*)(sw_b1 + quar * 4);
  float4 b1hi = *(const float4*)(sw_b1 + 16 + quar * 4);
  float4 w2lo0 = *(const float4*)(sw_w2 + quar * 4);
  float4 w2hi0 = *(const float4*)(sw_w2 + 16 + quar * 4);
  float4 w2lo1 = *(const float4*)(sw_w2 + 32 + quar * 4);
  float4 w2hi1 = *(const float4*)(sw_w2 + 48 + quar * 4);
  float r0 = fmaxf(hlo[0] + b1lo.x, 0.f), r1 = fmaxf(hlo[1] + b1lo.y, 0.f);
  float r2 = fmaxf(hlo[2] + b1lo.z, 0.f), r3 = fmaxf(hlo[3] + b1lo.w, 0.f);
  float r4 = fmaxf(hhi[0] + b1hi.x, 0.f), r5 = fmaxf(hhi[1] + b1hi.y, 0.f);
  float r6 = fmaxf(hhi[2] + b1hi.z, 0.f), r7 = fmaxf(hhi[3] + b1hi.w, 0.f);
  float zp0 = r0 * w2lo0.x + r1 * w2lo0.y + r2 * w2lo0.z + r3 * w2lo0.w +
              r4 * w2hi0.x + r5 * w2hi0.y + r6 * w2hi0.z + r7 * w2hi0.w;
  float zp1 = r0 * w2lo1.x + r1 * w2lo1.y + r2 * w2lo1.z + r3 * w2lo1.w +
              r4 * w2hi1.x + r5 * w2hi1.y + r6 * w2hi1.z + r7 * w2hi1.w;
  zp0 += __shfl_xor(zp0, 16); zp0 += __shfl_xor(zp0, 32);
  zp1 += __shfl_xor(zp1, 16); zp1 += __shfl_xor(zp1, 32);
  float s0 = 1.f / (1.f + __expf(-(zp0 + sw_b2[0])));
  float s1 = 1.f / (1.f + __expf(-(zp1 + sw_b2[1])));

  // xo channels [8*quar, 8*quar+8) of pixel pA == head `quar`'s q slice
  const float* ysp = y_sp + b * 32 + quar * 8;
  const float* ych = y_ch + b * 32 + quar * 8;
  float4 ga0 = ((const float4*)ysp)[0], ga1 = ((const float4*)ysp)[1];
  float4 gc0 = ((const float4*)ych)[0], gc1 = ((const float4*)ych)[1];
  float xo0 = xa0.x + ga0.x * s0 + gc0.x * s1;
  float xo1 = xa0.y + ga0.y * s0 + gc0.y * s1;
  float xo2 = xa0.z + ga0.z * s0 + gc0.z * s1;
  float xo3 = xa0.w + ga0.w * s0 + gc0.w * s1;
  float xo4 = xa1.x + ga1.x * s0 + gc1.x * s1;
  float xo5 = xa1.y + ga1.y * s0 + gc1.y * s1;
  float xo6 = xa1.z + ga1.z * s0 + gc1.z * s1;
  float xo7 = xa1.w + ga1.w * s0 + gc1.w * s1;
  xo_lds[quar][pA][0] = xo0; xo_lds[quar][pA][1] = xo1;
  xo_lds[quar][pA][2] = xo2; xo_lds[quar][pA][3] = xo3;
  xo_lds[quar][pA][4] = xo4; xo_lds[quar][pA][5] = xo5;
  xo_lds[quar][pA][6] = xo6; xo_lds[quar][pA][7] = xo7;
  {
    uint4 qp;
    qp.x = pk_bf16(xo0 * QSCALE, xo1 * QSCALE);
    qp.y = pk_bf16(xo2 * QSCALE, xo3 * QSCALE);
    qp.z = pk_bf16(xo4 * QSCALE, xo5 * QSCALE);
    qp.w = pk_bf16(xo6 * QSCALE, xo7 * QSCALE);
    *(uint4*)&qb_lds[quar][pA][0] = qp;
  }
  __syncthreads();

  // ---- phase B: attention, wave g = head g ----
  int g = wv;
  int px32 = lane & 31;
  int h2 = lane >> 5;
  const uint4* aq4 = (const uint4*)aq32;
  const uint4* apv4 = (const uint4*)apv32;

  U4S8 bq0, bq1;
  {
    uint4 q0 = *(const uint4*)&qb_lds[g][px32][0];
    uint4 q1 = *(const uint4*)&qb_lds[g][32 + px32][0];
    if (h2) { q0.x = q0.y = q0.z = q0.w = 0; q1.x = q1.y = q1.z = q1.w = 0; }
    bq0.u = q0; bq1.u = q1;
  }
  f32x16_t pvA = {0.f,0.f,0.f,0.f,0.f,0.f,0.f,0.f,0.f,0.f,0.f,0.f,0.f,0.f,0.f,0.f};
  f32x16_t pvB = pvA;

  for (int t32 = 0; t32 < 16; ++t32) {
    U4S8 aqf, ap0, ap1;
    aqf.u = aq4[((size_t)(g * 16 + t32)) * 64 + lane];
    ap0.u = apv4[((size_t)((g * 16 + t32) * 2 + 0)) * 64 + lane];
    ap1.u = apv4[((size_t)((g * 16 + t32) * 2 + 1)) * 64 + lane];
    attn_step(aqf.s, ap0.s, ap1.s, bq0.s, pvA);
    attn_step(aqf.s, ap0.s, ap1.s, bq1.s, pvB);
  }

  // epilogue: pv reg r (r<4) = d-row 4*h2+r; reg 4 (low half) = denom
  {
    float den = __shfl(pvA[4], px32);
    float linv = 1.f / den;
    int n = nbase + px32;
#pragma unroll
    for (int r = 0; r < 4; ++r) {
      float xo = xo_lds[g][px32][h2 * 4 + r];
      out[((size_t)(b * C_ + g * 8 + h2 * 4 + r)) * HW_ + n] = xo + pvA[r] * linv;
    }
  }
  {
    float den = __shfl(pvB[4], px32);
    float linv = 1.f / den;
    int n = nbase + 32 + px32;
#pragma unroll
    for (int r = 0; r < 4; ++r) {
      float xo = xo_lds[g][32 + px32][h2 * 4 + r];
      out[((size_t)(b * C_ + g * 8 + h2 * 4 + r)) * HW_ + n] = xo + pvB[r] * linv;
    }
  }
}

}  // namespace

extern "C" void kernel_launch(void* const* d_in, const int* in_sizes, int n_in,
                              void* d_out, int out_size, void* d_ws, size_t ws_size,
                              hipStream_t stream) {
  const float* x     = (const float*)d_in[0];
  const float* fs_w1 = (const float*)d_in[1];
  const float* fs_w2 = (const float*)d_in[2];
  const float* fc_w1 = (const float*)d_in[3];
  const float* fc_w2 = (const float*)d_in[4];
  const float* sw_w1 = (const float*)d_in[5];
  const float* sw_b1 = (const float*)d_in[6];
  const float* sw_w2 = (const float*)d_in[7];
  const float* sw_b2 = (const float*)d_in[8];
  const float* off_w = (const float*)d_in[9];
  const float* off_b = (const float*)d_in[10];
  const float* dcn_w = (const float*)d_in[11];
  const float* dcn_b = (const float*)d_in[12];
  const float* memw  = (const float*)d_in[13];
  float* out = (float*)d_out;

  float* ws = (float*)d_ws;
  float* y_sum  = ws;                 // 128
  float* y_sp   = ws + 128;           // 128
  float* y_ch   = ws + 256;           // 128
  float* x_hwc  = ws + 512;
  float* x3_hwc = x_hwc + (size_t)B_ * HW_ * C_;
  unsigned short* aoff_buf = (unsigned short*)(x3_hwc + (size_t)B_ * HW_ * C_);
  unsigned short* adcn_buf = aoff_buf + 9216;
  unsigned short* aq32_buf = adcn_buf + 9216;    // 32768 bf16
  unsigned short* apv_buf  = aq32_buf + 32768;   // 65536 bf16
  unsigned short* asw_buf  = apv_buf + 65536;    // 2048 bf16

  hipMemsetAsync((void*)y_sum, 0, 128 * sizeof(float), stream);
  hipLaunchKernelGGL(k_prep_frags, dim3(464), dim3(256), 0, stream,
                     off_w, dcn_w, memw, sw_w1, aoff_buf, adcn_buf, aq32_buf, apv_buf, asw_buf);
  hipLaunchKernelGGL(k_transpose, dim3(B_ * 256), dim3(256), 0, stream, x, x_hwc, y_sum);
  hipLaunchKernelGGL(k_se, dim3(1), dim3(128), 0, stream,
                     y_sum, fs_w1, fs_w2, fc_w1, fc_w2, y_sp, y_ch);
  hipLaunchKernelGGL(k_dcn, dim3(B_ * H_ * 2), dim3(256), 0, stream,
                     x, x_hwc, aoff_buf, off_b, adcn_buf, dcn_b, x3_hwc);
  hipLaunchKernelGGL(k_swattn, dim3(B_ * HW_ / 64), dim3(256), 0, stream,
                     x_hwc, x3_hwc, asw_buf, sw_b1, sw_w2, sw_b2, y_sp, y_ch,
                     aq32_buf, apv_buf, out);
}

// Round 7
// 166.167 us; speedup vs baseline: 2.7598x; 1.1833x over previous
//
#include <hip/hip_runtime.h>
#include <hip/hip_bf16.h>

namespace {

constexpr int B_ = 4, C_ = 32, H_ = 128, W_ = 128;
constexpr int HW_ = H_ * W_;
constexpr int MS_ = 512;
// fold (1/sqrt(8)) * log2(e) into q so scores feed exp2 directly
#define QSCALE 0.5100975104f

typedef short bf16x8_t __attribute__((ext_vector_type(8)));
typedef float f32x4_t __attribute__((ext_vector_type(4)));
typedef float f32x16_t __attribute__((ext_vector_type(16)));

union U4S8 { uint4 u; bf16x8_t s; };
union BF2U { __hip_bfloat162 h; unsigned u; };

__device__ inline unsigned pk_bf16(float lo, float hi) {
  BF2U t; t.h = __float22bfloat162_rn(float2{lo, hi}); return t.u;
}
__device__ inline unsigned short f2bf(float f) {
  unsigned u = __float_as_uint(f);
  return (unsigned short)((u + 0x7FFF + ((u >> 16) & 1)) >> 16);
}
__device__ inline float lo16(unsigned u) { return __uint_as_float(u << 16); }
__device__ inline float hi16(unsigned u) { return __uint_as_float(u & 0xffff0000u); }

// ---------------- 1. init: NCHW->NHWC transpose + mean partials + frag prep --
// Fragment layouts (verified on-device R4/R5):
//   16x16x32: A row=lane&15, K=(lane>>4)*8+j ; B col=lane&15 ; D col=lane&15,row=(lane>>4)*4+r
//   32x32x16: A row=lane&31, K=(lane>>5)*8+j ; D col=lane&31, row pairs per reg
__global__ void k_init(const float* __restrict__ x, float* __restrict__ x_hwc,
                       float* __restrict__ y_sum,
                       const float* __restrict__ off_w, const float* __restrict__ dcn_w,
                       const float* __restrict__ mem, const float* __restrict__ sw_w1,
                       unsigned short* __restrict__ aoff, unsigned short* __restrict__ adcn,
                       unsigned short* __restrict__ aq32, unsigned short* __restrict__ apv32,
                       unsigned short* __restrict__ asw) {
  __shared__ float tile[C_][65];
  int blk = blockIdx.x;
  int b = blk >> 8;
  int n0 = (blk & 255) << 6;
  int t = threadIdx.x;
#pragma unroll
  for (int i = 0; i < 8; ++i) {
    int l = t + (i << 8);
    int c = l >> 6, p = l & 63;
    tile[c][p] = x[((size_t)(b * C_ + c)) * HW_ + n0 + p];
  }
  __syncthreads();
#pragma unroll
  for (int i = 0; i < 8; ++i) {
    int l = t + (i << 8);
    int p = l >> 5, c = l & 31;
    x_hwc[((size_t)b * HW_ + n0 + p) * C_ + c] = tile[c][p];
  }
  // mean partial: thread (c = t>>3, ii = t&7) sums 8 px, 8-lane shuffle reduce
  {
    int c = t >> 3, ii = t & 7;
    float s = 0.f;
#pragma unroll
    for (int k = 0; k < 8; ++k) s += tile[c][ii * 8 + k];
    s += __shfl_xor(s, 1);
    s += __shfl_xor(s, 2);
    s += __shfl_xor(s, 4);
    if (ii == 0) atomicAdd(&y_sum[b * 32 + c], s);
  }
  // fragment prep (independent work, first 464 blocks' worth of ids)
  int i = blk * 256 + t;
  if (i < 9216) {
    int j = i & 7, l = (i >> 3) & 63, rest = i >> 9;
    int s = rest % 9, mt = rest / 9;
    int o = mt * 16 + (l & 15), c = (l >> 4) * 8 + j;
    aoff[i] = (o < 27) ? f2bf(off_w[((size_t)o * 32 + c) * 9 + s]) : (unsigned short)0;
  } else if (i < 18432) {
    int k = i - 9216;
    int j = k & 7, l = (k >> 3) & 63, rest = k >> 9;
    int s = rest % 9, mt = rest / 9;
    int o = mt * 16 + (l & 15), c = (l >> 4) * 8 + j;
    adcn[k] = f2bf(dcn_w[((size_t)o * 32 + c) * 9 + s]);
  } else if (i < 51200) {
    int k = i - 18432;
    int j = k & 7, l = (k >> 3) & 63, t32 = (k >> 9) & 15, h = k >> 13;
    int slot = t32 * 32 + (l & 31);
    aq32[k] = (l < 32) ? f2bf(mem[((size_t)h * MS_ + slot) * 8 + j]) : (unsigned short)0;
  } else if (i < 116736) {
    int k = i - 51200;
    int j = k & 7, l = (k >> 3) & 63, grp = (k >> 9) & 1, t32 = (k >> 10) & 15, h = k >> 14;
    int row = l & 31;
    int slot = t32 * 32 + grp * 16 + (l >> 5) * 8 + j;
    float v = (row < 8) ? mem[((size_t)h * MS_ + slot) * 8 + row] : (row == 8 ? 1.0f : 0.0f);
    apv32[k] = f2bf(v);
  } else if (i < 118784) {
    int k = i - 116736;
    int j = k & 7, l = (k >> 3) & 63, half = (k >> 9) & 1, kstep = (k >> 10) & 1;
    int o = half * 16 + (l & 15);
    int catc = kstep * 32 + (l >> 4) * 8 + j;
    asw[k] = f2bf(sw_w1[(size_t)o * 64 + catc]);
  }
}

// ---------------- 4. full-MFMA offset-conv + DCNv2, LDS sampling ----------
// Block = 256 thr = 4 waves over a 64-px half-row. 5-row x 68-col x 32ch bf16
// halo tile (rows y-2..y+2, cols x0-2..x0+65) serves offset-conv B-frags AND
// bilinear sampling (4 ds_read_b128/tap); rare out-of-tile corners fall back
// to global x_hwc. x3 written as packed bf16 pairs (switch B-frag layout).
__global__ __launch_bounds__(256, 4) void k_dcn(
    const float* __restrict__ x_hwc,  // (B,HW,C) fp32
    const unsigned short* __restrict__ aoff, const float* __restrict__ off_b,
    const unsigned short* __restrict__ adcn, const float* __restrict__ dcn_b,
    unsigned* __restrict__ x3b) {
  __shared__ __align__(16) unsigned short tileb[340 * 40];  // [pos=r*68+j][c], stride 40
  __shared__ __align__(16) float om_lds[64][28];

  int blk = blockIdx.x;
  int b = blk >> 8;
  int rem = blk & 255;
  int y = rem >> 1;
  int x0 = (rem & 1) << 6;
  int t = threadIdx.x;
  int w = t >> 6;
  int lane = t & 63;
  int quar = lane >> 4, px = lane & 15;
  int pxg = w * 16 + px;
  int xcol = x0 + pxg;
  const float* xb = x_hwc + (size_t)b * HW_ * C_;

  // --- stage 5x68 halo tile as bf16 via ds_write_b128 (task = pos,cq) ---
  for (int i = t; i < 1360; i += 256) {
    int pos = i >> 2, cq = i & 3;
    int r = pos / 68, j = pos - r * 68;
    int yy = y + r - 2, xx = x0 + j - 2;
    U4S8 pk4;
    if (yy >= 0 && yy < H_ && xx >= 0 && xx < W_) {
      const float4* s4 = (const float4*)(xb + ((size_t)yy * W_ + xx) * C_ + cq * 8);
      float4 a = s4[0], bb = s4[1];
      pk4.u.x = pk_bf16(a.x, a.y);  pk4.u.y = pk_bf16(a.z, a.w);
      pk4.u.z = pk_bf16(bb.x, bb.y); pk4.u.w = pk_bf16(bb.z, bb.w);
    } else {
      pk4.u.x = 0; pk4.u.y = 0; pk4.u.z = 0; pk4.u.w = 0;
    }
    *(uint4*)&tileb[pos * 40 + cq * 8] = pk4.u;
  }
  __syncthreads();

  // --- GEMM1: offset conv via MFMA (K = tap*32 + c) ---
  const uint4* aoff4 = (const uint4*)aoff;
  f32x4_t acc0 = {0.f, 0.f, 0.f, 0.f}, acc1 = {0.f, 0.f, 0.f, 0.f};
#pragma unroll
  for (int s = 0; s < 9; ++s) {
    int r = s / 3, dx = s % 3;
    int pos = (r + 1) * 68 + pxg + dx + 1;
    U4S8 a0, a1, bv;
    a0.u = aoff4[s * 64 + lane];
    a1.u = aoff4[(9 + s) * 64 + lane];
    bv.u = *(const uint4*)&tileb[pos * 40 + quar * 8];
    acc0 = __builtin_amdgcn_mfma_f32_16x16x32_bf16(a0.s, bv.s, acc0, 0, 0, 0);
    acc1 = __builtin_amdgcn_mfma_f32_16x16x32_bf16(a1.s, bv.s, acc1, 0, 0, 0);
  }
#pragma unroll
  for (int r = 0; r < 4; ++r) {
    int o = quar * 4 + r;
    om_lds[pxg][o] = acc0[r] + off_b[o];
  }
#pragma unroll
  for (int r = 0; r < 4; ++r) {
    int o = 16 + quar * 4 + r;
    if (o < 27) om_lds[pxg][o] = acc1[r] + off_b[o];
  }
  __syncthreads();

  // --- sampling (LDS, global fallback) + GEMM2 (K = k*32 + c) ---
  const uint4* adcn4 = (const uint4*)adcn;
  f32x4_t o0 = {0.f, 0.f, 0.f, 0.f}, o1 = {0.f, 0.f, 0.f, 0.f};
#pragma unroll
  for (int k = 0; k < 9; ++k) {
    int ky = k / 3 - 1, kx = k % 3 - 1;
    float py = (float)(y + ky) + om_lds[pxg][2 * k];
    float pxf = (float)(xcol + kx) + om_lds[pxg][2 * k + 1];
    float mask = 1.f / (1.f + __expf(-om_lds[pxg][18 + k]));
    float y0f = floorf(py), x0f = floorf(pxf);
    float wy = py - y0f, wx = pxf - x0f;
    int yi0 = (int)y0f, xi0 = (int)x0f;

    float samp[8];
#pragma unroll
    for (int cc = 0; cc < 8; ++cc) samp[cc] = 0.f;
#pragma unroll
    for (int cy = 0; cy < 2; ++cy) {
      int yi = yi0 + cy;
      float wgy = cy ? wy : 1.f - wy;
#pragma unroll
      for (int cx = 0; cx < 2; ++cx) {
        int xi = xi0 + cx;
        float wgt = wgy * (cx ? wx : 1.f - wx);
        int rr = yi - y + 2, jj = xi - x0 + 2;
        if (rr >= 0 && rr <= 4 && jj >= 0 && jj <= 67) {
          // in-tile (zero-filled outside image == reference valid-mask)
          uint4 rw = *(const uint4*)&tileb[(rr * 68 + jj) * 40 + quar * 8];
          samp[0] += wgt * lo16(rw.x); samp[1] += wgt * hi16(rw.x);
          samp[2] += wgt * lo16(rw.y); samp[3] += wgt * hi16(rw.y);
          samp[4] += wgt * lo16(rw.z); samp[5] += wgt * hi16(rw.z);
          samp[6] += wgt * lo16(rw.w); samp[7] += wgt * hi16(rw.w);
        } else if (yi >= 0 && yi < H_ && xi >= 0 && xi < W_) {
          // rare: in-image but out-of-tile
          const float4* s4 = (const float4*)(xb + ((size_t)yi * W_ + xi) * C_ + quar * 8);
          float4 a = s4[0], bb = s4[1];
          samp[0] += wgt * a.x;  samp[1] += wgt * a.y;
          samp[2] += wgt * a.z;  samp[3] += wgt * a.w;
          samp[4] += wgt * bb.x; samp[5] += wgt * bb.y;
          samp[6] += wgt * bb.z; samp[7] += wgt * bb.w;
        }
      }
    }
    U4S8 bs, a0, a1;
    bs.u.x = pk_bf16(samp[0] * mask, samp[1] * mask);
    bs.u.y = pk_bf16(samp[2] * mask, samp[3] * mask);
    bs.u.z = pk_bf16(samp[4] * mask, samp[5] * mask);
    bs.u.w = pk_bf16(samp[6] * mask, samp[7] * mask);
    a0.u = adcn4[k * 64 + lane];
    a1.u = adcn4[(9 + k) * 64 + lane];
    o0 = __builtin_amdgcn_mfma_f32_16x16x32_bf16(a0.s, bs.s, o0, 0, 0, 0);
    o1 = __builtin_amdgcn_mfma_f32_16x16x32_bf16(a1.s, bs.s, o1, 0, 0, 0);
  }

  // --- epilogue: D + bias -> packed bf16 (switch B-frag layout) ---
  float4 db0 = *(const float4*)(dcn_b + quar * 4);
  float4 db1 = *(const float4*)(dcn_b + 16 + quar * 4);
  unsigned w0 = pk_bf16(o0[0] + db0.x, o0[1] + db0.y);
  unsigned w1 = pk_bf16(o0[2] + db0.z, o0[3] + db0.w);
  unsigned w2 = pk_bf16(o1[0] + db1.x, o1[1] + db1.y);
  unsigned w3 = pk_bf16(o1[2] + db1.z, o1[3] + db1.w);
  unsigned* dst = x3b + ((size_t)b * HW_ + y * W_ + xcol) * 16;
  uint2 lo2; lo2.x = w0; lo2.y = w1;
  uint2 hi2; hi2.x = w2; hi2.y = w3;
  *(uint2*)(dst + quar * 2) = lo2;        // channel pairs quar*2, quar*2+1
  *(uint2*)(dst + 8 + quar * 2) = hi2;    // channel pairs 8+quar*2, ..+1
}

// ---------------- 5. fused SE + switch + gating + 32x32-MFMA attention -----
__device__ inline void attn_step(const bf16x8_t aqf, const bf16x8_t ap0, const bf16x8_t ap1,
                                 const bf16x8_t bq, f32x16_t& acc) {
  f32x16_t zz = {0.f,0.f,0.f,0.f,0.f,0.f,0.f,0.f,0.f,0.f,0.f,0.f,0.f,0.f,0.f,0.f};
  f32x16_t d = __builtin_amdgcn_mfma_f32_32x32x16_bf16(aqf, bq, zz, 0, 0, 0);
  unsigned w[8];
#pragma unroll
  for (int v = 0; v < 8; ++v) w[v] = pk_bf16(exp2f(d[2 * v]), exp2f(d[2 * v + 1]));
  asm("v_permlane32_swap_b32 %0, %1" : "+v"(w[2]), "+v"(w[0]));
  asm("v_permlane32_swap_b32 %0, %1" : "+v"(w[3]), "+v"(w[1]));
  asm("v_permlane32_swap_b32 %0, %1" : "+v"(w[6]), "+v"(w[4]));
  asm("v_permlane32_swap_b32 %0, %1" : "+v"(w[7]), "+v"(w[5]));
  U4S8 f1, f2;
  f1.u.x = w[0]; f1.u.y = w[1]; f1.u.z = w[2]; f1.u.w = w[3];
  f2.u.x = w[4]; f2.u.y = w[5]; f2.u.z = w[6]; f2.u.w = w[7];
  acc = __builtin_amdgcn_mfma_f32_32x32x16_bf16(ap0, f1.s, acc, 0, 0, 0);
  acc = __builtin_amdgcn_mfma_f32_32x32x16_bf16(ap1, f2.s, acc, 0, 0, 0);
}

__global__ __launch_bounds__(256, 2) void k_swattn(
    const float* __restrict__ x_hwc, const unsigned* __restrict__ x3b,
    const unsigned short* __restrict__ asw, const float* __restrict__ sw_b1,
    const float* __restrict__ sw_w2, const float* __restrict__ sw_b2,
    const float* __restrict__ y_sum,
    const float* __restrict__ fs_w1, const float* __restrict__ fs_w2,
    const float* __restrict__ fc_w1, const float* __restrict__ fc_w2,
    const unsigned short* __restrict__ aq32, const unsigned short* __restrict__ apv32,
    float* __restrict__ out) {
  __shared__ float xo_lds[4][65][9];
  __shared__ __align__(16) unsigned qb_lds[4][65][4];

  int t = threadIdx.x;
  int wv = __builtin_amdgcn_readfirstlane(t >> 6);
  int lane = t & 63;
  int quar = lane >> 4, px16 = lane & 15;
  int pix0 = blockIdx.x * 64;
  int b = blockIdx.x >> 8;
  int nbase = pix0 & (HW_ - 1);

  // ---- inline SE: gates for channels quar*8..+8 of this batch ----
  float ysp[8], ych[8];
  {
    float ya[32];
    const float* ysrc = y_sum + b * 32;
#pragma unroll
    for (int j = 0; j < 32; ++j) ya[j] = ysrc[j] * (1.f / HW_);
    float h0 = 0.f, h1 = 0.f;
#pragma unroll
    for (int j = 0; j < 32; ++j) { h0 += ya[j] * fs_w1[j]; h1 += ya[j] * fs_w1[32 + j]; }
    h0 = fmaxf(h0, 0.f); h1 = fmaxf(h1, 0.f);
    float hh0 = 0.f, hh1 = 0.f, hh2 = 0.f, hh3 = 0.f;
#pragma unroll
    for (int j = 0; j < 32; ++j) {
      hh0 += ya[j] * fc_w1[j];
      hh1 += ya[j] * fc_w1[32 + j];
      hh2 += ya[j] * fc_w1[64 + j];
      hh3 += ya[j] * fc_w1[96 + j];
    }
    hh0 = fmaxf(hh0, 0.f); hh1 = fmaxf(hh1, 0.f);
    hh2 = fmaxf(hh2, 0.f); hh3 = fmaxf(hh3, 0.f);
#pragma unroll
    for (int d = 0; d < 8; ++d) {
      int c = quar * 8 + d;
      float z = h0 * fs_w2[c * 2] + h1 * fs_w2[c * 2 + 1];
      ysp[d] = 1.f / (1.f + __expf(-z));
      float z2 = hh0 * fc_w2[c * 4] + hh1 * fc_w2[c * 4 + 1] +
                 hh2 * fc_w2[c * 4 + 2] + hh3 * fc_w2[c * 4 + 3];
      ych[d] = 1.f / (1.f + __expf(-z2));
    }
  }

  // ---- phase A: switch conv via MFMA; wave wv owns pixels [16wv,16wv+16) ----
  int pA = wv * 16 + px16;
  int pix = pix0 + pA;
  const float* xp = x_hwc + (size_t)pix * C_ + quar * 8;
  float4 xa0 = ((const float4*)xp)[0], xa1 = ((const float4*)xp)[1];
  U4S8 bx, bx3;
  bx.u.x = pk_bf16(xa0.x, xa0.y); bx.u.y = pk_bf16(xa0.z, xa0.w);
  bx.u.z = pk_bf16(xa1.x, xa1.y); bx.u.w = pk_bf16(xa1.z, xa1.w);
  bx3.u = *(const uint4*)(x3b + (size_t)pix * 16 + quar * 4);

  const uint4* asw4 = (const uint4*)asw;
  U4S8 a00, a01, a10, a11;
  a00.u = asw4[0 * 64 + lane];
  a01.u = asw4[1 * 64 + lane];
  a10.u = asw4[2 * 64 + lane];
  a11.u = asw4[3 * 64 + lane];
  f32x4_t z4 = {0.f, 0.f, 0.f, 0.f};
  f32x4_t hlo = __builtin_amdgcn_mfma_f32_16x16x32_bf16(a00.s, bx.s, z4, 0, 0, 0);
  hlo = __builtin_amdgcn_mfma_f32_16x16x32_bf16(a10.s, bx3.s, hlo, 0, 0, 0);
  f32x4_t hhi = __builtin_amdgcn_mfma_f32_16x16x32_bf16(a01.s, bx.s, z4, 0, 0, 0);
  hhi = __builtin_amdgcn_mfma_f32_16x16x32_bf16(a11.s, bx3.s, hhi, 0, 0, 0);

  float4 b1lo = *(const float4*)(sw_b1 + quar * 4);
  float4 b1hi = *(const float4*)(sw_b1 + 16 + quar * 4);
  float4 w2lo0 = *(const float4*)(sw_w2 + quar * 4);
  float4 w2hi0 = *(const float4*)(sw_w2 + 16 + quar * 4);
  float4 w2lo1 = *(const float4*)(sw_w2 + 32 + quar * 4);
  float4 w2hi1 = *(const float4*)(sw_w2 + 48 + quar * 4);
  float r0 = fmaxf(hlo[0] + b1lo.x, 0.f), r1 = fmaxf(hlo[1] + b1lo.y, 0.f);
  float r2 = fmaxf(hlo[2] + b1lo.z, 0.f), r3 = fmaxf(hlo[3] + b1lo.w, 0.f);
  float r4 = fmaxf(hhi[0] + b1hi.x, 0.f), r5 = fmaxf(hhi[1] + b1hi.y, 0.f);
  float r6 = fmaxf(hhi[2] + b1hi.z, 0.f), r7 = fmaxf(hhi[3] + b1hi.w, 0.f);
  float zp0 = r0 * w2lo0.x + r1 * w2lo0.y + r2 * w2lo0.z + r3 * w2lo0.w +
              r4 * w2hi0.x + r5 * w2hi0.y + r6 * w2hi0.z + r7 * w2hi0.w;
  float zp1 = r0 * w2lo1.x + r1 * w2lo1.y + r2 * w2lo1.z + r3 * w2lo1.w +
              r4 * w2hi1.x + r5 * w2hi1.y + r6 * w2hi1.z + r7 * w2hi1.w;
  zp0 += __shfl_xor(zp0, 16); zp0 += __shfl_xor(zp0, 32);
  zp1 += __shfl_xor(zp1, 16); zp1 += __shfl_xor(zp1, 32);
  float s0 = 1.f / (1.f + __expf(-(zp0 + sw_b2[0])));
  float s1 = 1.f / (1.f + __expf(-(zp1 + sw_b2[1])));

  float xo0 = xa0.x + ysp[0] * s0 + ych[0] * s1;
  float xo1 = xa0.y + ysp[1] * s0 + ych[1] * s1;
  float xo2 = xa0.z + ysp[2] * s0 + ych[2] * s1;
  float xo3 = xa0.w + ysp[3] * s0 + ych[3] * s1;
  float xo4 = xa1.x + ysp[4] * s0 + ych[4] * s1;
  float xo5 = xa1.y + ysp[5] * s0 + ych[5] * s1;
  float xo6 = xa1.z + ysp[6] * s0 + ych[6] * s1;
  float xo7 = xa1.w + ysp[7] * s0 + ych[7] * s1;
  xo_lds[quar][pA][0] = xo0; xo_lds[quar][pA][1] = xo1;
  xo_lds[quar][pA][2] = xo2; xo_lds[quar][pA][3] = xo3;
  xo_lds[quar][pA][4] = xo4; xo_lds[quar][pA][5] = xo5;
  xo_lds[quar][pA][6] = xo6; xo_lds[quar][pA][7] = xo7;
  {
    uint4 qp;
    qp.x = pk_bf16(xo0 * QSCALE, xo1 * QSCALE);
    qp.y = pk_bf16(xo2 * QSCALE, xo3 * QSCALE);
    qp.z = pk_bf16(xo4 * QSCALE, xo5 * QSCALE);
    qp.w = pk_bf16(xo6 * QSCALE, xo7 * QSCALE);
    *(uint4*)&qb_lds[quar][pA][0] = qp;
  }
  __syncthreads();

  // ---- phase B: attention, wave g = head g ----
  int g = wv;
  int px32 = lane & 31;
  int h2 = lane >> 5;
  const uint4* aq4 = (const uint4*)aq32;
  const uint4* apv4 = (const uint4*)apv32;

  U4S8 bq0, bq1;
  {
    uint4 q0 = *(const uint4*)&qb_lds[g][px32][0];
    uint4 q1 = *(const uint4*)&qb_lds[g][32 + px32][0];
    if (h2) { q0.x = q0.y = q0.z = q0.w = 0; q1.x = q1.y = q1.z = q1.w = 0; }
    bq0.u = q0; bq1.u = q1;
  }
  f32x16_t pvA = {0.f,0.f,0.f,0.f,0.f,0.f,0.f,0.f,0.f,0.f,0.f,0.f,0.f,0.f,0.f,0.f};
  f32x16_t pvB = pvA;

  for (int t32 = 0; t32 < 16; ++t32) {
    U4S8 aqf, ap0, ap1;
    aqf.u = aq4[((size_t)(g * 16 + t32)) * 64 + lane];
    ap0.u = apv4[((size_t)((g * 16 + t32) * 2 + 0)) * 64 + lane];
    ap1.u = apv4[((size_t)((g * 16 + t32) * 2 + 1)) * 64 + lane];
    attn_step(aqf.s, ap0.s, ap1.s, bq0.s, pvA);
    attn_step(aqf.s, ap0.s, ap1.s, bq1.s, pvB);
  }

  {
    float den = __shfl(pvA[4], px32);
    float linv = 1.f / den;
    int n = nbase + px32;
#pragma unroll
    for (int r = 0; r < 4; ++r) {
      float xo = xo_lds[g][px32][h2 * 4 + r];
      out[((size_t)(b * C_ + g * 8 + h2 * 4 + r)) * HW_ + n] = xo + pvA[r] * linv;
    }
  }
  {
    float den = __shfl(pvB[4], px32);
    float linv = 1.f / den;
    int n = nbase + 32 + px32;
#pragma unroll
    for (int r = 0; r < 4; ++r) {
      float xo = xo_lds[g][32 + px32][h2 * 4 + r];
      out[((size_t)(b * C_ + g * 8 + h2 * 4 + r)) * HW_ + n] = xo + pvB[r] * linv;
    }
  }
}

}  // namespace

extern "C" void kernel_launch(void* const* d_in, const int* in_sizes, int n_in,
                              void* d_out, int out_size, void* d_ws, size_t ws_size,
                              hipStream_t stream) {
  const float* x     = (const float*)d_in[0];
  const float* fs_w1 = (const float*)d_in[1];
  const float* fs_w2 = (const float*)d_in[2];
  const float* fc_w1 = (const float*)d_in[3];
  const float* fc_w2 = (const float*)d_in[4];
  const float* sw_w1 = (const float*)d_in[5];
  const float* sw_b1 = (const float*)d_in[6];
  const float* sw_w2 = (const float*)d_in[7];
  const float* sw_b2 = (const float*)d_in[8];
  const float* off_w = (const float*)d_in[9];
  const float* off_b = (const float*)d_in[10];
  const float* dcn_w = (const float*)d_in[11];
  const float* dcn_b = (const float*)d_in[12];
  const float* memw  = (const float*)d_in[13];
  float* out = (float*)d_out;

  float* ws = (float*)d_ws;
  float* y_sum = ws;                              // 128
  float* x_hwc = ws + 128;                        // 2M floats
  unsigned* x3b = (unsigned*)(x_hwc + (size_t)B_ * HW_ * C_);   // 1M u32 (bf16 pairs)
  unsigned short* aoff_buf = (unsigned short*)(x3b + (size_t)B_ * HW_ * 16);
  unsigned short* adcn_buf = aoff_buf + 9216;
  unsigned short* aq32_buf = adcn_buf + 9216;     // 32768 bf16
  unsigned short* apv_buf  = aq32_buf + 32768;    // 65536 bf16
  unsigned short* asw_buf  = apv_buf + 65536;     // 2048 bf16

  hipMemsetAsync((void*)y_sum, 0, 128 * sizeof(float), stream);
  hipLaunchKernelGGL(k_init, dim3(B_ * 256), dim3(256), 0, stream,
                     x, x_hwc, y_sum, off_w, dcn_w, memw, sw_w1,
                     aoff_buf, adcn_buf, aq32_buf, apv_buf, asw_buf);
  hipLaunchKernelGGL(k_dcn, dim3(B_ * H_ * 2), dim3(256), 0, stream,
                     x_hwc, aoff_buf, off_b, adcn_buf, dcn_b, x3b);
  hipLaunchKernelGGL(k_swattn, dim3(B_ * HW_ / 64), dim3(256), 0, stream,
                     x_hwc, x3b, asw_buf, sw_b1, sw_w2, sw_b2,
                     y_sum, fs_w1, fs_w2, fc_w1, fc_w2,
                     aq32_buf, apv_buf, out);
}

// Round 10
// 151.932 us; speedup vs baseline: 3.0184x; 1.0937x over previous
//
#include <hip/hip_runtime.h>
#include <hip/hip_bf16.h>

namespace {

constexpr int B_ = 4, C_ = 32, H_ = 128, W_ = 128;
constexpr int HW_ = H_ * W_;
constexpr int MS_ = 512;
// fold (1/sqrt(8)) * log2(e) into q so scores feed exp2 directly
#define QSCALE 0.5100975104f

typedef short bf16x8_t __attribute__((ext_vector_type(8)));
typedef float f32x4_t __attribute__((ext_vector_type(4)));
typedef float f32x16_t __attribute__((ext_vector_type(16)));

union U4S8 { uint4 u; bf16x8_t s; };
union BF2U { __hip_bfloat162 h; unsigned u; };

__device__ inline unsigned pk_bf16(float lo, float hi) {
  BF2U t; t.h = __float22bfloat162_rn(float2{lo, hi}); return t.u;
}
__device__ inline unsigned short f2bf(float f) {
  unsigned u = __float_as_uint(f);
  return (unsigned short)((u + 0x7FFF + ((u >> 16) & 1)) >> 16);
}
__device__ inline float lo16(unsigned u) { return __uint_as_float(u << 16); }
__device__ inline float hi16(unsigned u) { return __uint_as_float(u & 0xffff0000u); }
// bare v_exp_f32 (2^x) via intrinsic: backend-visible trans op -> hazard-safe
__device__ inline float fast_exp2(float x) {
  return __builtin_amdgcn_exp2f(x);
}

// ---------------- 1. init: NCHW->NHWC transpose + mean partials + frag prep --
// Fragment layouts (verified on-device R4/R5):
//   16x16x32: A row=lane&15, K=(lane>>4)*8+j ; B col=lane&15 ; D col=lane&15,row=(lane>>4)*4+r
//   32x32x16: A row=lane&31, K=(lane>>5)*8+j ; D col=lane&31, row=(reg&3)+8*(reg>>2)+4*(lane>>5)
__global__ void k_init(const float* __restrict__ x, float* __restrict__ x_hwc,
                       float* __restrict__ y_sum,
                       const float* __restrict__ off_w, const float* __restrict__ dcn_w,
                       const float* __restrict__ mem, const float* __restrict__ sw_w1,
                       unsigned short* __restrict__ aoff, unsigned short* __restrict__ adcn,
                       unsigned short* __restrict__ aq32, unsigned short* __restrict__ apv32,
                       unsigned short* __restrict__ asw) {
  __shared__ float tile[C_][65];
  int blk = blockIdx.x;
  int b = blk >> 8;
  int n0 = (blk & 255) << 6;
  int t = threadIdx.x;
#pragma unroll
  for (int i = 0; i < 8; ++i) {
    int l = t + (i << 8);
    int c = l >> 6, p = l & 63;
    tile[c][p] = x[((size_t)(b * C_ + c)) * HW_ + n0 + p];
  }
  __syncthreads();
#pragma unroll
  for (int i = 0; i < 8; ++i) {
    int l = t + (i << 8);
    int p = l >> 5, c = l & 31;
    x_hwc[((size_t)b * HW_ + n0 + p) * C_ + c] = tile[c][p];
  }
  // mean partial
  {
    int c = t >> 3, ii = t & 7;
    float s = 0.f;
#pragma unroll
    for (int k = 0; k < 8; ++k) s += tile[c][ii * 8 + k];
    s += __shfl_xor(s, 1);
    s += __shfl_xor(s, 2);
    s += __shfl_xor(s, 4);
    if (ii == 0) atomicAdd(&y_sum[b * 32 + c], s);
  }
  // fragment prep
  int i = blk * 256 + t;
  if (i < 9216) {
    int j = i & 7, l = (i >> 3) & 63, rest = i >> 9;
    int s = rest % 9, mt = rest / 9;
    int o = mt * 16 + (l & 15), c = (l >> 4) * 8 + j;
    aoff[i] = (o < 27) ? f2bf(off_w[((size_t)o * 32 + c) * 9 + s]) : (unsigned short)0;
  } else if (i < 18432) {
    int k = i - 9216;
    int j = k & 7, l = (k >> 3) & 63, rest = k >> 9;
    int s = rest % 9, mt = rest / 9;
    int o = mt * 16 + (l & 15), c = (l >> 4) * 8 + j;
    adcn[k] = f2bf(dcn_w[((size_t)o * 32 + c) * 9 + s]);
  } else if (i < 51200) {
    int k = i - 18432;
    int j = k & 7, l = (k >> 3) & 63, t32 = (k >> 9) & 15, h = k >> 13;
    int slot = t32 * 32 + (l & 31);
    aq32[k] = (l < 32) ? f2bf(mem[((size_t)h * MS_ + slot) * 8 + j]) : (unsigned short)0;
  } else if (i < 116736) {
    int k = i - 51200;
    int j = k & 7, l = (k >> 3) & 63, grp = (k >> 9) & 1, t32 = (k >> 10) & 15, h = k >> 14;
    int row = l & 31;
    int slot = t32 * 32 + grp * 16 + (l >> 5) * 8 + j;
    float v = (row < 8) ? mem[((size_t)h * MS_ + slot) * 8 + row] : (row == 8 ? 1.0f : 0.0f);
    apv32[k] = f2bf(v);
  } else if (i < 118784) {
    int k = i - 116736;
    int j = k & 7, l = (k >> 3) & 63, half = (k >> 9) & 1, kstep = (k >> 10) & 1;
    int o = half * 16 + (l & 15);
    int catc = kstep * 32 + (l >> 4) * 8 + j;
    asw[k] = f2bf(sw_w1[(size_t)o * 64 + catc]);
  }
}

// ---------------- 4. full-MFMA offset-conv + DCNv2, LDS sampling ----------
__global__ __launch_bounds__(256, 4) void k_dcn(
    const float* __restrict__ x_hwc,  // (B,HW,C) fp32
    const unsigned short* __restrict__ aoff, const float* __restrict__ off_b,
    const unsigned short* __restrict__ adcn, const float* __restrict__ dcn_b,
    unsigned* __restrict__ x3b) {
  __shared__ __align__(16) unsigned short tileb[340 * 40];  // [pos=r*68+j][c]
  __shared__ __align__(16) float om_lds[64][29];            // stride 29: conflict-free

  int blk = blockIdx.x;
  int b = blk >> 8;
  int rem = blk & 255;
  int y = rem >> 1;
  int x0 = (rem & 1) << 6;
  int t = threadIdx.x;
  int w = t >> 6;
  int lane = t & 63;
  int quar = lane >> 4, px = lane & 15;
  int pxg = w * 16 + px;
  int xcol = x0 + pxg;
  const float* xb = x_hwc + (size_t)b * HW_ * C_;

  // --- stage 5x68 halo tile as bf16 via ds_write_b128 (task = pos,cq) ---
  for (int i = t; i < 1360; i += 256) {
    int pos = i >> 2, cq = i & 3;
    int r = pos / 68, j = pos - r * 68;
    int yy = y + r - 2, xx = x0 + j - 2;
    U4S8 pk4;
    if (yy >= 0 && yy < H_ && xx >= 0 && xx < W_) {
      const float4* s4 = (const float4*)(xb + ((size_t)yy * W_ + xx) * C_ + cq * 8);
      float4 a = s4[0], bb = s4[1];
      pk4.u.x = pk_bf16(a.x, a.y);  pk4.u.y = pk_bf16(a.z, a.w);
      pk4.u.z = pk_bf16(bb.x, bb.y); pk4.u.w = pk_bf16(bb.z, bb.w);
    } else {
      pk4.u.x = 0; pk4.u.y = 0; pk4.u.z = 0; pk4.u.w = 0;
    }
    *(uint4*)&tileb[pos * 40 + cq * 8] = pk4.u;
  }
  __syncthreads();

  // --- GEMM1: offset conv via MFMA (K = tap*32 + c) ---
  const uint4* aoff4 = (const uint4*)aoff;
  f32x4_t acc0 = {0.f, 0.f, 0.f, 0.f}, acc1 = {0.f, 0.f, 0.f, 0.f};
#pragma unroll
  for (int s = 0; s < 9; ++s) {
    int r = s / 3, dx = s % 3;
    int pos = (r + 1) * 68 + pxg + dx + 1;
    U4S8 a0, a1, bv;
    a0.u = aoff4[s * 64 + lane];
    a1.u = aoff4[(9 + s) * 64 + lane];
    bv.u = *(const uint4*)&tileb[pos * 40 + quar * 8];
    acc0 = __builtin_amdgcn_mfma_f32_16x16x32_bf16(a0.s, bv.s, acc0, 0, 0, 0);
    acc1 = __builtin_amdgcn_mfma_f32_16x16x32_bf16(a1.s, bv.s, acc1, 0, 0, 0);
  }
#pragma unroll
  for (int r = 0; r < 4; ++r) {
    int o = quar * 4 + r;
    om_lds[pxg][o] = acc0[r] + off_b[o];
  }
#pragma unroll
  for (int r = 0; r < 4; ++r) {
    int o = 16 + quar * 4 + r;
    if (o < 27) om_lds[pxg][o] = acc1[r] + off_b[o];
  }
  __syncthreads();

  // --- sampling (LDS, global fallback) + GEMM2 (K = k*32 + c) ---
  const uint4* adcn4 = (const uint4*)adcn;
  f32x4_t o0 = {0.f, 0.f, 0.f, 0.f}, o1 = {0.f, 0.f, 0.f, 0.f};
#pragma unroll
  for (int k = 0; k < 9; ++k) {
    int ky = k / 3 - 1, kx = k % 3 - 1;
    float py = (float)(y + ky) + om_lds[pxg][2 * k];
    float pxf = (float)(xcol + kx) + om_lds[pxg][2 * k + 1];
    float mask = 1.f / (1.f + __expf(-om_lds[pxg][18 + k]));
    float y0f = floorf(py), x0f = floorf(pxf);
    float wy = py - y0f, wx = pxf - x0f;
    int yi0 = (int)y0f, xi0 = (int)x0f;

    float samp[8];
#pragma unroll
    for (int cc = 0; cc < 8; ++cc) samp[cc] = 0.f;
#pragma unroll
    for (int cy = 0; cy < 2; ++cy) {
      int yi = yi0 + cy;
      float wgy = cy ? wy : 1.f - wy;
#pragma unroll
      for (int cx = 0; cx < 2; ++cx) {
        int xi = xi0 + cx;
        float wgt = wgy * (cx ? wx : 1.f - wx);
        int rr = yi - y + 2, jj = xi - x0 + 2;
        if (rr >= 0 && rr <= 4 && jj >= 0 && jj <= 67) {
          uint4 rw = *(const uint4*)&tileb[(rr * 68 + jj) * 40 + quar * 8];
          samp[0] += wgt * lo16(rw.x); samp[1] += wgt * hi16(rw.x);
          samp[2] += wgt * lo16(rw.y); samp[3] += wgt * hi16(rw.y);
          samp[4] += wgt * lo16(rw.z); samp[5] += wgt * hi16(rw.z);
          samp[6] += wgt * lo16(rw.w); samp[7] += wgt * hi16(rw.w);
        } else if (yi >= 0 && yi < H_ && xi >= 0 && xi < W_) {
          const float4* s4 = (const float4*)(xb + ((size_t)yi * W_ + xi) * C_ + quar * 8);
          float4 a = s4[0], bb = s4[1];
          samp[0] += wgt * a.x;  samp[1] += wgt * a.y;
          samp[2] += wgt * a.z;  samp[3] += wgt * a.w;
          samp[4] += wgt * bb.x; samp[5] += wgt * bb.y;
          samp[6] += wgt * bb.z; samp[7] += wgt * bb.w;
        }
      }
    }
    U4S8 bs, a0, a1;
    bs.u.x = pk_bf16(samp[0] * mask, samp[1] * mask);
    bs.u.y = pk_bf16(samp[2] * mask, samp[3] * mask);
    bs.u.z = pk_bf16(samp[4] * mask, samp[5] * mask);
    bs.u.w = pk_bf16(samp[6] * mask, samp[7] * mask);
    a0.u = adcn4[k * 64 + lane];
    a1.u = adcn4[(9 + k) * 64 + lane];
    o0 = __builtin_amdgcn_mfma_f32_16x16x32_bf16(a0.s, bs.s, o0, 0, 0, 0);
    o1 = __builtin_amdgcn_mfma_f32_16x16x32_bf16(a1.s, bs.s, o1, 0, 0, 0);
  }

  // --- epilogue: D + bias -> packed bf16 (switch B-frag layout) ---
  float4 db0 = *(const float4*)(dcn_b + quar * 4);
  float4 db1 = *(const float4*)(dcn_b + 16 + quar * 4);
  unsigned w0 = pk_bf16(o0[0] + db0.x, o0[1] + db0.y);
  unsigned w1 = pk_bf16(o0[2] + db0.z, o0[3] + db0.w);
  unsigned w2 = pk_bf16(o1[0] + db1.x, o1[1] + db1.y);
  unsigned w3 = pk_bf16(o1[2] + db1.z, o1[3] + db1.w);
  unsigned* dst = x3b + ((size_t)b * HW_ + y * W_ + xcol) * 16;
  uint2 lo2; lo2.x = w0; lo2.y = w1;
  uint2 hi2; hi2.x = w2; hi2.y = w3;
  *(uint2*)(dst + quar * 2) = lo2;
  *(uint2*)(dst + 8 + quar * 2) = hi2;
}

// ---------------- 5. fused SE + switch + gating + 32x32-MFMA attention -----
__device__ inline void attn_step(const bf16x8_t aqf, const bf16x8_t ap0, const bf16x8_t ap1,
                                 const bf16x8_t bq, const f32x16_t& zz, f32x16_t& acc) {
  f32x16_t d = __builtin_amdgcn_mfma_f32_32x32x16_bf16(aqf, bq, zz, 0, 0, 0);
  unsigned w[8];
#pragma unroll
  for (int v = 0; v < 8; ++v)
    w[v] = pk_bf16(fast_exp2(d[2 * v]), fast_exp2(d[2 * v + 1]));
  asm("v_permlane32_swap_b32 %0, %1" : "+v"(w[2]), "+v"(w[0]));
  asm("v_permlane32_swap_b32 %0, %1" : "+v"(w[3]), "+v"(w[1]));
  asm("v_permlane32_swap_b32 %0, %1" : "+v"(w[6]), "+v"(w[4]));
  asm("v_permlane32_swap_b32 %0, %1" : "+v"(w[7]), "+v"(w[5]));
  U4S8 f1, f2;
  f1.u.x = w[0]; f1.u.y = w[1]; f1.u.z = w[2]; f1.u.w = w[3];
  f2.u.x = w[4]; f2.u.y = w[5]; f2.u.z = w[6]; f2.u.w = w[7];
  acc = __builtin_amdgcn_mfma_f32_32x32x16_bf16(ap0, f1.s, acc, 0, 0, 0);
  acc = __builtin_amdgcn_mfma_f32_32x32x16_bf16(ap1, f2.s, acc, 0, 0, 0);
}

__global__ __launch_bounds__(256, 2) void k_swattn(
    const float* __restrict__ x_hwc, const unsigned* __restrict__ x3b,
    const unsigned short* __restrict__ asw, const float* __restrict__ sw_b1,
    const float* __restrict__ sw_w2, const float* __restrict__ sw_b2,
    const float* __restrict__ y_sum,
    const float* __restrict__ fs_w1, const float* __restrict__ fs_w2,
    const float* __restrict__ fc_w1, const float* __restrict__ fc_w2,
    const unsigned short* __restrict__ aq32, const unsigned short* __restrict__ apv32,
    float* __restrict__ out) {
  __shared__ float xo_lds[4][65][9];
  __shared__ __align__(16) unsigned qb_lds[4][65][4];

  int t = threadIdx.x;
  int wv = __builtin_amdgcn_readfirstlane(t >> 6);
  int lane = t & 63;
  int quar = lane >> 4, px16 = lane & 15;
  int pix0 = blockIdx.x * 64;
  int b = blockIdx.x >> 8;
  int nbase = pix0 & (HW_ - 1);

  // ---- inline SE ----
  float ysp[8], ych[8];
  {
    float ya[32];
    const float* ysrc = y_sum + b * 32;
#pragma unroll
    for (int j = 0; j < 32; ++j) ya[j] = ysrc[j] * (1.f / HW_);
    float h0 = 0.f, h1 = 0.f;
#pragma unroll
    for (int j = 0; j < 32; ++j) { h0 += ya[j] * fs_w1[j]; h1 += ya[j] * fs_w1[32 + j]; }
    h0 = fmaxf(h0, 0.f); h1 = fmaxf(h1, 0.f);
    float hh0 = 0.f, hh1 = 0.f, hh2 = 0.f, hh3 = 0.f;
#pragma unroll
    for (int j = 0; j < 32; ++j) {
      hh0 += ya[j] * fc_w1[j];
      hh1 += ya[j] * fc_w1[32 + j];
      hh2 += ya[j] * fc_w1[64 + j];
      hh3 += ya[j] * fc_w1[96 + j];
    }
    hh0 = fmaxf(hh0, 0.f); hh1 = fmaxf(hh1, 0.f);
    hh2 = fmaxf(hh2, 0.f); hh3 = fmaxf(hh3, 0.f);
#pragma unroll
    for (int d = 0; d < 8; ++d) {
      int c = quar * 8 + d;
      float z = h0 * fs_w2[c * 2] + h1 * fs_w2[c * 2 + 1];
      ysp[d] = 1.f / (1.f + __expf(-z));
      float z2 = hh0 * fc_w2[c * 4] + hh1 * fc_w2[c * 4 + 1] +
                 hh2 * fc_w2[c * 4 + 2] + hh3 * fc_w2[c * 4 + 3];
      ych[d] = 1.f / (1.f + __expf(-z2));
    }
  }

  // ---- phase A: switch conv via MFMA ----
  int pA = wv * 16 + px16;
  int pix = pix0 + pA;
  const float* xp = x_hwc + (size_t)pix * C_ + quar * 8;
  float4 xa0 = ((const float4*)xp)[0], xa1 = ((const float4*)xp)[1];
  U4S8 bx, bx3;
  bx.u.x = pk_bf16(xa0.x, xa0.y); bx.u.y = pk_bf16(xa0.z, xa0.w);
  bx.u.z = pk_bf16(xa1.x, xa1.y); bx.u.w = pk_bf16(xa1.z, xa1.w);
  bx3.u = *(const uint4*)(x3b + (size_t)pix * 16 + quar * 4);

  const uint4* asw4 = (const uint4*)asw;
  U4S8 a00, a01, a10, a11;
  a00.u = asw4[0 * 64 + lane];
  a01.u = asw4[1 * 64 + lane];
  a10.u = asw4[2 * 64 + lane];
  a11.u = asw4[3 * 64 + lane];
  f32x4_t z4 = {0.f, 0.f, 0.f, 0.f};
  f32x4_t hlo = __builtin_amdgcn_mfma_f32_16x16x32_bf16(a00.s, bx.s, z4, 0, 0, 0);
  hlo = __builtin_amdgcn_mfma_f32_16x16x32_bf16(a10.s, bx3.s, hlo, 0, 0, 0);
  f32x4_t hhi = __builtin_amdgcn_mfma_f32_16x16x32_bf16(a01.s, bx.s, z4, 0, 0, 0);
  hhi = __builtin_amdgcn_mfma_f32_16x16x32_bf16(a11.s, bx3.s, hhi, 0, 0, 0);

  float4 b1lo = *(const float4*)(sw_b1 + quar * 4);
  float4 b1hi = *(const float4*)(sw_b1 + 16 + quar * 4);
  float4 w2lo0 = *(const float4*)(sw_w2 + quar * 4);
  float4 w2hi0 = *(const float4*)(sw_w2 + 16 + quar * 4);
  float4 w2lo1 = *(const float4*)(sw_w2 + 32 + quar * 4);
  float4 w2hi1 = *(const float4*)(sw_w2 + 48 + quar * 4);
  float r0 = fmaxf(hlo[0] + b1lo.x, 0.f), r1 = fmaxf(hlo[1] + b1lo.y, 0.f);
  float r2 = fmaxf(hlo[2] + b1lo.z, 0.f), r3 = fmaxf(hlo[3] + b1lo.w, 0.f);
  float r4 = fmaxf(hhi[0] + b1hi.x, 0.f), r5 = fmaxf(hhi[1] + b1hi.y, 0.f);
  float r6 = fmaxf(hhi[2] + b1hi.z, 0.f), r7 = fmaxf(hhi[3] + b1hi.w, 0.f);
  float zp0 = r0 * w2lo0.x + r1 * w2lo0.y + r2 * w2lo0.z + r3 * w2lo0.w +
              r4 * w2hi0.x + r5 * w2hi0.y + r6 * w2hi0.z + r7 * w2hi0.w;
  float zp1 = r0 * w2lo1.x + r1 * w2lo1.y + r2 * w2lo1.z + r3 * w2lo1.w +
              r4 * w2hi1.x + r5 * w2hi1.y + r6 * w2hi1.z + r7 * w2hi1.w;
  zp0 += __shfl_xor(zp0, 16); zp0 += __shfl_xor(zp0, 32);
  zp1 += __shfl_xor(zp1, 16); zp1 += __shfl_xor(zp1, 32);
  float s0 = 1.f / (1.f + __expf(-(zp0 + sw_b2[0])));
  float s1 = 1.f / (1.f + __expf(-(zp1 + sw_b2[1])));

  float xo0 = xa0.x + ysp[0] * s0 + ych[0] * s1;
  float xo1 = xa0.y + ysp[1] * s0 + ych[1] * s1;
  float xo2 = xa0.z + ysp[2] * s0 + ych[2] * s1;
  float xo3 = xa0.w + ysp[3] * s0 + ych[3] * s1;
  float xo4 = xa1.x + ysp[4] * s0 + ych[4] * s1;
  float xo5 = xa1.y + ysp[5] * s0 + ych[5] * s1;
  float xo6 = xa1.z + ysp[6] * s0 + ych[6] * s1;
  float xo7 = xa1.w + ysp[7] * s0 + ych[7] * s1;
  xo_lds[quar][pA][0] = xo0; xo_lds[quar][pA][1] = xo1;
  xo_lds[quar][pA][2] = xo2; xo_lds[quar][pA][3] = xo3;
  xo_lds[quar][pA][4] = xo4; xo_lds[quar][pA][5] = xo5;
  xo_lds[quar][pA][6] = xo6; xo_lds[quar][pA][7] = xo7;
  {
    uint4 qp;
    qp.x = pk_bf16(xo0 * QSCALE, xo1 * QSCALE);
    qp.y = pk_bf16(xo2 * QSCALE, xo3 * QSCALE);
    qp.z = pk_bf16(xo4 * QSCALE, xo5 * QSCALE);
    qp.w = pk_bf16(xo6 * QSCALE, xo7 * QSCALE);
    *(uint4*)&qb_lds[quar][pA][0] = qp;
  }
  __syncthreads();

  // ---- phase B: attention, wave g = head g ----
  int g = wv;
  int px32 = lane & 31;
  int h2 = lane >> 5;
  const uint4* aq4 = (const uint4*)aq32;
  const uint4* apv4 = (const uint4*)apv32;

  U4S8 bq0, bq1;
  {
    uint4 q0 = *(const uint4*)&qb_lds[g][px32][0];
    uint4 q1 = *(const uint4*)&qb_lds[g][32 + px32][0];
    if (h2) { q0.x = q0.y = q0.z = q0.w = 0; q1.x = q1.y = q1.z = q1.w = 0; }
    bq0.u = q0; bq1.u = q1;
  }
  const f32x16_t zz = {0.f,0.f,0.f,0.f,0.f,0.f,0.f,0.f,0.f,0.f,0.f,0.f,0.f,0.f,0.f,0.f};
  f32x16_t pvA = zz;
  f32x16_t pvB = zz;

  for (int t32 = 0; t32 < 16; ++t32) {
    U4S8 aqf, ap0, ap1;
    aqf.u = aq4[((size_t)(g * 16 + t32)) * 64 + lane];
    ap0.u = apv4[((size_t)((g * 16 + t32) * 2 + 0)) * 64 + lane];
    ap1.u = apv4[((size_t)((g * 16 + t32) * 2 + 1)) * 64 + lane];
    attn_step(aqf.s, ap0.s, ap1.s, bq0.s, zz, pvA);
    attn_step(aqf.s, ap0.s, ap1.s, bq1.s, zz, pvB);
  }

  {
    float den = __shfl(pvA[4], px32);
    float linv = 1.f / den;
    int n = nbase + px32;
#pragma unroll
    for (int r = 0; r < 4; ++r) {
      float xo = xo_lds[g][px32][h2 * 4 + r];
      out[((size_t)(b * C_ + g * 8 + h2 * 4 + r)) * HW_ + n] = xo + pvA[r] * linv;
    }
  }
  {
    float den = __shfl(pvB[4], px32);
    float linv = 1.f / den;
    int n = nbase + 32 + px32;
#pragma unroll
    for (int r = 0; r < 4; ++r) {
      float xo = xo_lds[g][32 + px32][h2 * 4 + r];
      out[((size_t)(b * C_ + g * 8 + h2 * 4 + r)) * HW_ + n] = xo + pvB[r] * linv;
    }
  }
}

}  // namespace

extern "C" void kernel_launch(void* const* d_in, const int* in_sizes, int n_in,
                              void* d_out, int out_size, void* d_ws, size_t ws_size,
                              hipStream_t stream) {
  const float* x     = (const float*)d_in[0];
  const float* fs_w1 = (const float*)d_in[1];
  const float* fs_w2 = (const float*)d_in[2];
  const float* fc_w1 = (const float*)d_in[3];
  const float* fc_w2 = (const float*)d_in[4];
  const float* sw_w1 = (const float*)d_in[5];
  const float* sw_b1 = (const float*)d_in[6];
  const float* sw_w2 = (const float*)d_in[7];
  const float* sw_b2 = (const float*)d_in[8];
  const float* off_w = (const float*)d_in[9];
  const float* off_b = (const float*)d_in[10];
  const float* dcn_w = (const float*)d_in[11];
  const float* dcn_b = (const float*)d_in[12];
  const float* memw  = (const float*)d_in[13];
  float* out = (float*)d_out;

  float* ws = (float*)d_ws;
  float* y_sum = ws;                              // 128
  float* x_hwc = ws + 128;                        // 2M floats
  unsigned* x3b = (unsigned*)(x_hwc + (size_t)B_ * HW_ * C_);   // 1M u32 (bf16 pairs)
  unsigned short* aoff_buf = (unsigned short*)(x3b + (size_t)B_ * HW_ * 16);
  unsigned short* adcn_buf = aoff_buf + 9216;
  unsigned short* aq32_buf = adcn_buf + 9216;     // 32768 bf16
  unsigned short* apv_buf  = aq32_buf + 32768;    // 65536 bf16
  unsigned short* asw_buf  = apv_buf + 65536;     // 2048 bf16

  hipMemsetAsync((void*)y_sum, 0, 128 * sizeof(float), stream);
  hipLaunchKernelGGL(k_init, dim3(B_ * 256), dim3(256), 0, stream,
                     x, x_hwc, y_sum, off_w, dcn_w, memw, sw_w1,
                     aoff_buf, adcn_buf, aq32_buf, apv_buf, asw_buf);
  hipLaunchKernelGGL(k_dcn, dim3(B_ * H_ * 2), dim3(256), 0, stream,
                     x_hwc, aoff_buf, off_b, adcn_buf, dcn_b, x3b);
  hipLaunchKernelGGL(k_swattn, dim3(B_ * HW_ / 64), dim3(256), 0, stream,
                     x_hwc, x3b, asw_buf, sw_b1, sw_w2, sw_b2,
                     y_sum, fs_w1, fs_w2, fc_w1, fc_w2,
                     aq32_buf, apv_buf, out);
}